// Round 9
// baseline (632.856 us; speedup 1.0000x reference)
//
#include <hip/hip_runtime.h>

// Problem constants — NOTE: BS=4 (H, DH, BS, NSEL, WIN = 16, 64, 4, 4, 32)
constexpr int cH = 16, cDH = 64, cBS = 4, cNSEL = 4, cWIN = 32;
constexpr int cB = 2, cS = 1024, cD = 1024;
constexpr int cNB = 256, cNBLK = 257, cDFF = 4096, cM = 2048; // cM = B*S
constexpr float cSCALE = 0.125f; // DH^-0.5
constexpr int cSSTR = 258; // old scalar cattn ssb stride
constexpr int cNP = 288;   // padded compressed-block count

typedef unsigned short u16;
typedef unsigned int u32;
typedef __attribute__((ext_vector_type(8))) __bf16 bf16x8;
typedef __attribute__((ext_vector_type(8))) u16 u16x8;
typedef __attribute__((ext_vector_type(4))) float f32x4;
static_assert(sizeof(bf16x8) == 16, "bf16x8 must be 16B");

__device__ __forceinline__ float sigf(float x) { return 1.f / (1.f + expf(-x)); }
__device__ __forceinline__ float b2f(u16 u) {
  union { float f; u32 u; } c; c.u = ((u32)u) << 16; return c.f;
}
__device__ __forceinline__ u16 f2b(float f) {
  union { float f; u32 u; } c; c.f = f;
  u32 u = c.u;
  return (u16)((u + 0x7fffu + ((u >> 16) & 1u)) >> 16); // RNE
}
__device__ __forceinline__ void split_bf(float v, u16& h, u16& l) {
  h = f2b(v);
  l = f2b(v - b2f(h)); // exact residual, then RNE
}

// async global->LDS, 16B per lane; LDS dest must be wave-uniform base + lane*16
typedef const __attribute__((address_space(1))) void* gas_t;
typedef __attribute__((address_space(3))) void* las_t;
__device__ __forceinline__ void gload16(void* lds, const void* g) {
  __builtin_amdgcn_global_load_lds((gas_t)g, (las_t)lds, 16, 0, 0);
}

__global__ __launch_bounds__(256) void k_fill(float* __restrict__ p, float v)
{
  p[blockIdx.x * 256 + threadIdx.x] = v;
}

// ---------------- xr = l0*x + l1*x0 ; h = rmsnorm(xr) (+ optional bf16 hi/lo) ----------------
__global__ __launch_bounds__(256) void k_lerp_rmsnorm(
    const float* __restrict__ x, const float* __restrict__ x0,
    const float* __restrict__ lambdas, float* __restrict__ xr, float* __restrict__ h,
    u16* __restrict__ hbh, u16* __restrict__ hbl)
{
  int row = blockIdx.x, tid = threadIdx.x;
  float l0 = lambdas[0], l1 = lambdas[1];
  size_t base = (size_t)row * cD + tid * 4;
  float4 xa = *(const float4*)(x + base);
  float4 xb = *(const float4*)(x0 + base);
  float v0 = l0 * xa.x + l1 * xb.x;
  float v1 = l0 * xa.y + l1 * xb.y;
  float v2 = l0 * xa.z + l1 * xb.z;
  float v3 = l0 * xa.w + l1 * xb.w;
  float ss = v0*v0 + v1*v1 + v2*v2 + v3*v3;
  #pragma unroll
  for (int o = 32; o; o >>= 1) ss += __shfl_xor(ss, o);
  __shared__ float red[4];
  if ((tid & 63) == 0) red[tid >> 6] = ss;
  __syncthreads();
  float tot = red[0] + red[1] + red[2] + red[3];
  float sc = rsqrtf(tot * (1.0f / cD) + 1e-6f);
  *(float4*)(xr + base) = make_float4(v0, v1, v2, v3);
  float h0 = v0*sc, h1 = v1*sc, h2 = v2*sc, h3 = v3*sc;
  *(float4*)(h + base) = make_float4(h0, h1, h2, h3);
  if (hbh) {
    ushort4 hv, lv;
    split_bf(h0, hv.x, lv.x); split_bf(h1, hv.y, lv.y);
    split_bf(h2, hv.z, lv.z); split_bf(h3, hv.w, lv.w);
    *(ushort4*)(hbh + base) = hv;
    *(ushort4*)(hbl + base) = lv;
  }
}

// ---------------- rmsnorm: f32 out and/or bf16 hi/lo out ----------------
__global__ __launch_bounds__(256) void k_rmsnorm(
    const float* __restrict__ x, float* __restrict__ out,
    u16* __restrict__ obh, u16* __restrict__ obl)
{
  int row = blockIdx.x, tid = threadIdx.x;
  size_t base = (size_t)row * cD + tid * 4;
  float4 v = *(const float4*)(x + base);
  float ss = v.x*v.x + v.y*v.y + v.z*v.z + v.w*v.w;
  #pragma unroll
  for (int o = 32; o; o >>= 1) ss += __shfl_xor(ss, o);
  __shared__ float red[4];
  if ((tid & 63) == 0) red[tid >> 6] = ss;
  __syncthreads();
  float tot = red[0] + red[1] + red[2] + red[3];
  float sc = rsqrtf(tot * (1.0f / cD) + 1e-6f);
  float h0 = v.x*sc, h1 = v.y*sc, h2 = v.z*sc, h3 = v.w*sc;
  if (out) *(float4*)(out + base) = make_float4(h0, h1, h2, h3);
  if (obh) {
    ushort4 hv, lv;
    split_bf(h0, hv.x, lv.x); split_bf(h1, hv.y, lv.y);
    split_bf(h2, hv.z, lv.z); split_bf(h3, hv.w, lv.w);
    *(ushort4*)(obh + base) = hv;
    *(ushort4*)(obl + base) = lv;
  }
}

// ---------------- tiled f32 GEMM (fallback path only) ----------------
template<int EPI>
__global__ __launch_bounds__(256) void k_gemm(
    const float* __restrict__ A, const float* __restrict__ Bw,
    const float* __restrict__ R, float* __restrict__ C, int M, int N, int K)
{
  constexpr int BM = 64, BN = 64, BK = 16;
  __shared__ float As[BK][BM];
  __shared__ float Bs[BK][BN];
  int tid = threadIdx.x;
  int tx = tid & 15, ty = tid >> 4;
  int m0 = blockIdx.y * BM, n0 = blockIdx.x * BN;
  float acc[4][4] = {};
  for (int k0 = 0; k0 < K; k0 += BK) {
    {
      int r = tid >> 2, c4 = (tid & 3) << 2;
      float4 av = *(const float4*)(A + (size_t)(m0 + r) * K + k0 + c4);
      As[c4+0][r] = av.x; As[c4+1][r] = av.y; As[c4+2][r] = av.z; As[c4+3][r] = av.w;
    }
    {
      int kr = tid >> 4, c4 = (tid & 15) << 2;
      int n = n0 + c4;
      const float* bp = Bw + (size_t)(k0 + kr) * N;
      if (n + 3 < N) {
        float4 bv = *(const float4*)(bp + n);
        Bs[kr][c4+0] = bv.x; Bs[kr][c4+1] = bv.y; Bs[kr][c4+2] = bv.z; Bs[kr][c4+3] = bv.w;
      } else {
        #pragma unroll
        for (int j = 0; j < 4; j++) Bs[kr][c4+j] = (n + j < N) ? bp[n + j] : 0.f;
      }
    }
    __syncthreads();
    #pragma unroll
    for (int kk = 0; kk < BK; ++kk) {
      float4 a4 = *(const float4*)&As[kk][ty << 2];
      float4 b4 = *(const float4*)&Bs[kk][tx << 2];
      float av[4] = {a4.x, a4.y, a4.z, a4.w};
      float bv[4] = {b4.x, b4.y, b4.z, b4.w};
      #pragma unroll
      for (int i = 0; i < 4; i++)
        #pragma unroll
        for (int j = 0; j < 4; j++) acc[i][j] += av[i] * bv[j];
    }
    __syncthreads();
  }
  #pragma unroll
  for (int i = 0; i < 4; i++) {
    int m = m0 + (ty << 2) + i;
    #pragma unroll
    for (int j = 0; j < 4; j++) {
      int n = n0 + (tx << 2) + j;
      if (n < N) {
        float vv = acc[i][j];
        if (EPI == 1) vv = vv > 0.f ? vv * vv : 0.f;
        if (R) vv += R[(size_t)m * N + n];
        C[(size_t)m * N + n] = vv;
      }
    }
  }
}

// ---------------- weight transpose + bf16 hi/lo split: W(K,N) -> Th/Tl (N,K) ----------------
__global__ __launch_bounds__(256) void k_wsplit_t(
    const float* __restrict__ W, u16* __restrict__ Th, u16* __restrict__ Tl, int K, int N)
{
  __shared__ float tile[32][33];
  int n0 = blockIdx.x * 32, k0 = blockIdx.y * 32;
  int r = threadIdx.x >> 3, c4 = (threadIdx.x & 7) << 2;
  float4 v = *(const float4*)(W + (size_t)(k0 + r) * N + n0 + c4);
  tile[r][c4+0] = v.x; tile[r][c4+1] = v.y; tile[r][c4+2] = v.z; tile[r][c4+3] = v.w;
  __syncthreads();
  float f0 = tile[c4+0][r], f1 = tile[c4+1][r], f2 = tile[c4+2][r], f3 = tile[c4+3][r];
  ushort4 hv, lv;
  split_bf(f0, hv.x, lv.x); split_bf(f1, hv.y, lv.y);
  split_bf(f2, hv.z, lv.z); split_bf(f3, hv.w, lv.w);
  size_t ob = (size_t)(n0 + r) * K + k0 + c4;
  *(ushort4*)(Th + ob) = hv;
  *(ushort4*)(Tl + ob) = lv;
}

// ---------------- Wg (1024,48) -> padded transpose (64,1024) bf16 hi/lo ----------------
__global__ __launch_bounds__(256) void k_wsplit_g(
    const float* __restrict__ W, u16* __restrict__ Th, u16* __restrict__ Tl)
{
  int idx = blockIdx.x * 256 + threadIdx.x; // < 65536
  int n = idx >> 10, kk = idx & 1023;
  float v = (n < 48) ? W[(size_t)kk * 48 + n] : 0.f;
  u16 hb, lb; split_bf(v, hb, lb);
  Th[idx] = hb; Tl[idx] = lb;
}

// ---------------- split-bf16 MFMA GEMM v2: BK=64, XOR-swizzled LDS, XCD swizzle ------------
template<int BM, int BN, int EPI, int OUTBF, int TERMS>
__global__ __launch_bounds__(256) void k_mfma_gemm(
    const u16* __restrict__ Ah_g, const u16* __restrict__ Al_g,
    const u16* __restrict__ Bh_g, const u16* __restrict__ Bl_g,
    const float* __restrict__ R, float* __restrict__ Cf,
    u16* __restrict__ Ch, u16* __restrict__ Cl,
    int M, int N, int K)
{
  constexpr int BK = 64;
  constexpr int MR = BM / 32, NR = BN / 32;
  __shared__ u16 lds[(BM + BN) * BK * 2];
  u16* Ah = lds;
  u16* Al = Ah + BM * BK;
  u16* Bh = Al + BM * BK;
  u16* Bl = Bh + BN * BK;

  int tid = threadIdx.x;
  int lane = tid & 63, wave = tid >> 6;
  int wr = wave >> 1, wc = wave & 1;
  int l16 = lane & 15, rg = lane >> 4;

  int nwg = gridDim.x * gridDim.y;
  int lin = blockIdx.y * gridDim.x + blockIdx.x;
  if ((nwg & 7) == 0) lin = (lin & 7) * (nwg >> 3) + (lin >> 3);
  int m0 = (lin / gridDim.x) * BM, n0 = (lin % gridDim.x) * BN;

  f32x4 acc[MR][NR];
  #pragma unroll
  for (int m = 0; m < MR; m++)
    #pragma unroll
    for (int n = 0; n < NR; n++) acc[m][n] = (f32x4){0.f, 0.f, 0.f, 0.f};

  for (int k0 = 0; k0 < K; k0 += BK) {
    #pragma unroll
    for (int c = tid; c < BM * 8; c += 256) {
      int row = c >> 3, gs = (c & 7) ^ (row & 7);
      size_t off = (size_t)(m0 + row) * K + k0 + (gs << 3);
      gload16(Ah + c * 8, Ah_g + off);
      gload16(Al + c * 8, Al_g + off);
    }
    #pragma unroll
    for (int c = tid; c < BN * 8; c += 256) {
      int row = c >> 3, gs = (c & 7) ^ (row & 7);
      size_t off = (size_t)(n0 + row) * K + k0 + (gs << 3);
      gload16(Bh + c * 8, Bh_g + off);
      gload16(Bl + c * 8, Bl_g + off);
    }
    __syncthreads(); // drains vmcnt -> staged data visible

    #pragma unroll
    for (int ks = 0; ks < 2; ks++) {
      bf16x8 ah[MR], al[MR];
      #pragma unroll
      for (int m = 0; m < MR; m++) {
        int r = wr * (BM / 2) + m * 16 + l16;
        int sl = ((ks << 2) + rg) ^ (r & 7);
        ah[m] = *(const bf16x8*)&Ah[r * BK + (sl << 3)];
        al[m] = *(const bf16x8*)&Al[r * BK + (sl << 3)];
      }
      #pragma unroll
      for (int n = 0; n < NR; n++) {
        int r = wc * (BN / 2) + n * 16 + l16;
        int sl = ((ks << 2) + rg) ^ (r & 7);
        bf16x8 bh = *(const bf16x8*)&Bh[r * BK + (sl << 3)];
        bf16x8 bl = *(const bf16x8*)&Bl[r * BK + (sl << 3)];
        #pragma unroll
        for (int m = 0; m < MR; m++) {
          acc[m][n] = __builtin_amdgcn_mfma_f32_16x16x32_bf16(ah[m], bh, acc[m][n], 0, 0, 0);
          acc[m][n] = __builtin_amdgcn_mfma_f32_16x16x32_bf16(ah[m], bl, acc[m][n], 0, 0, 0);
          acc[m][n] = __builtin_amdgcn_mfma_f32_16x16x32_bf16(al[m], bh, acc[m][n], 0, 0, 0);
          if (TERMS == 4)
            acc[m][n] = __builtin_amdgcn_mfma_f32_16x16x32_bf16(al[m], bl, acc[m][n], 0, 0, 0);
        }
      }
    }
    __syncthreads();
  }

  int rbase = m0 + wr * (BM / 2) + (rg << 2);
  #pragma unroll
  for (int m = 0; m < MR; m++) {
    #pragma unroll
    for (int j = 0; j < 4; j++) {
      int row = rbase + m * 16 + j;
      #pragma unroll
      for (int n = 0; n < NR; n++) {
        int col = n0 + wc * (BN / 2) + n * 16 + l16;
        float v = acc[m][n][j];
        if (EPI == 1) v = v > 0.f ? v * v : 0.f;
        if (R) v += R[(size_t)row * N + col];
        if (OUTBF != 1) Cf[(size_t)row * N + col] = v;
        if (OUTBF >= 1) {
          u16 hb, lb; split_bf(v, hb, lb);
          Ch[(size_t)row * N + col] = hb;
          Cl[(size_t)row * N + col] = lb;
        }
      }
    }
  }
}

// ---------------- fused q|k|v|g GEMM: N = 3*1024 + 64(padded g), 4-term split-bf16 ---------
__global__ __launch_bounds__(256) void k_mfma_qkvg(
    const u16* __restrict__ Ahg, const u16* __restrict__ Alg,
    const u16* __restrict__ BqH, const u16* __restrict__ BqL,
    const u16* __restrict__ BkH, const u16* __restrict__ BkL,
    const u16* __restrict__ BvH, const u16* __restrict__ BvL,
    const u16* __restrict__ BgH, const u16* __restrict__ BgL,
    float* __restrict__ qo, float* __restrict__ ko, float* __restrict__ vo,
    float* __restrict__ gpre, u16* __restrict__ qbh, u16* __restrict__ qbl)
{
  constexpr int BM = 64, BN = 64, BK = 64, K = cD;
  __shared__ u16 lds[(BM + BN) * BK * 2];
  u16* Ah = lds;
  u16* Al = Ah + BM * BK;
  u16* Bh = Al + BM * BK;
  u16* Bl = Bh + BN * BK;

  int tid = threadIdx.x;
  int lane = tid & 63, wave = tid >> 6;
  int wr = wave >> 1, wc = wave & 1;
  int l16 = lane & 15, rg = lane >> 4;

  int nwg = gridDim.x * gridDim.y; // 1568 = 8*196
  int lin = blockIdx.y * gridDim.x + blockIdx.x;
  lin = (lin & 7) * (nwg >> 3) + (lin >> 3);
  int bx = lin % gridDim.x, by = lin / gridDim.x;
  int mat = bx >> 4; // 0=q 1=k 2=v 3=g (bx==48)
  int n0 = (bx - (mat << 4)) * BN;
  int m0 = by * BM;

  const u16* Bh_g; const u16* Bl_g;
  if (mat == 0)      { Bh_g = BqH; Bl_g = BqL; }
  else if (mat == 1) { Bh_g = BkH; Bl_g = BkL; }
  else if (mat == 2) { Bh_g = BvH; Bl_g = BvL; }
  else               { Bh_g = BgH; Bl_g = BgL; }

  f32x4 acc[2][2];
  #pragma unroll
  for (int m = 0; m < 2; m++)
    #pragma unroll
    for (int n = 0; n < 2; n++) acc[m][n] = (f32x4){0.f, 0.f, 0.f, 0.f};

  for (int k0 = 0; k0 < K; k0 += BK) {
    #pragma unroll
    for (int c = tid; c < BM * 8; c += 256) {
      int row = c >> 3, gs = (c & 7) ^ (row & 7);
      size_t off = (size_t)(m0 + row) * K + k0 + (gs << 3);
      gload16(Ah + c * 8, Ahg + off);
      gload16(Al + c * 8, Alg + off);
    }
    #pragma unroll
    for (int c = tid; c < BN * 8; c += 256) {
      int row = c >> 3, gs = (c & 7) ^ (row & 7);
      size_t off = (size_t)(n0 + row) * K + k0 + (gs << 3);
      gload16(Bh + c * 8, Bh_g + off);
      gload16(Bl + c * 8, Bl_g + off);
    }
    __syncthreads();

    #pragma unroll
    for (int ks = 0; ks < 2; ks++) {
      bf16x8 ah[2], al[2];
      #pragma unroll
      for (int m = 0; m < 2; m++) {
        int r = wr * 32 + m * 16 + l16;
        int sl = ((ks << 2) + rg) ^ (r & 7);
        ah[m] = *(const bf16x8*)&Ah[r * BK + (sl << 3)];
        al[m] = *(const bf16x8*)&Al[r * BK + (sl << 3)];
      }
      #pragma unroll
      for (int n = 0; n < 2; n++) {
        int r = wc * 32 + n * 16 + l16;
        int sl = ((ks << 2) + rg) ^ (r & 7);
        bf16x8 bh = *(const bf16x8*)&Bh[r * BK + (sl << 3)];
        bf16x8 bl = *(const bf16x8*)&Bl[r * BK + (sl << 3)];
        #pragma unroll
        for (int m = 0; m < 2; m++) {
          acc[m][n] = __builtin_amdgcn_mfma_f32_16x16x32_bf16(ah[m], bh, acc[m][n], 0, 0, 0);
          acc[m][n] = __builtin_amdgcn_mfma_f32_16x16x32_bf16(ah[m], bl, acc[m][n], 0, 0, 0);
          acc[m][n] = __builtin_amdgcn_mfma_f32_16x16x32_bf16(al[m], bh, acc[m][n], 0, 0, 0);
          acc[m][n] = __builtin_amdgcn_mfma_f32_16x16x32_bf16(al[m], bl, acc[m][n], 0, 0, 0);
        }
      }
    }
    __syncthreads();
  }

  int rbase = m0 + wr * 32 + (rg << 2);
  #pragma unroll
  for (int m = 0; m < 2; m++) {
    #pragma unroll
    for (int j = 0; j < 4; j++) {
      int row = rbase + m * 16 + j;
      #pragma unroll
      for (int n = 0; n < 2; n++) {
        int col = n0 + wc * 32 + n * 16 + l16;
        float v = acc[m][n][j];
        if (mat == 0) {
          qo[(size_t)row * cD + col] = v;
          u16 hb, lb; split_bf(v, hb, lb);
          qbh[(size_t)row * cD + col] = hb;
          qbl[(size_t)row * cD + col] = lb;
        } else if (mat == 1) {
          ko[(size_t)row * cD + col] = v;
        } else if (mat == 2) {
          vo[(size_t)row * cD + col] = v;
        } else if (col < 48) {
          gpre[(size_t)row * 48 + col] = v;
        }
      }
    }
  }
}

// ---------------- block compression, f32 out (fallback path only) ----------------
__global__ __launch_bounds__(64) void k_compress4(
    const float* __restrict__ kbuf, const float* __restrict__ vbuf,
    const float* __restrict__ pos_k, const float* __restrict__ pos_v,
    const float* __restrict__ Wck, const float* __restrict__ Wcv,
    const float* __restrict__ mem_k, const float* __restrict__ mem_v,
    float* __restrict__ kc, float* __restrict__ vc)
{
  int idx = blockIdx.x;          // b*NBLK*H + n*H + h
  int h = idx % cH; int n = (idx / cH) % cNBLK; int b = idx / (cH * cNBLK);
  int d = threadIdx.x;
  size_t co = (((size_t)b * cNBLK + n) * cH + h) * cDH + d;
  if (n == 0) {
    kc[co] = mem_k[h * cDH + d];
    vc[co] = mem_v[h * cDH + d];
    return;
  }
  __shared__ float kb[cBS * cDH], vb[cBS * cDH];
  int nb = n - 1;
  for (int t = d; t < cBS * cDH; t += 64) {
    int i = t >> 6, e = t & 63;
    size_t src = (((size_t)b * cS + nb * cBS + i) * cH + h) * cDH + e;
    kb[t] = kbuf[src] + pos_k[(h * cBS + i) * cDH + e];
    vb[t] = vbuf[src] + pos_v[(h * cBS + i) * cDH + e];
  }
  __syncthreads();
  float ak = 0.f, av = 0.f;
  #pragma unroll 4
  for (int j = 0; j < cBS * cDH; ++j) {
    ak += kb[j] * Wck[(size_t)j * cDH + d];
    av += vb[j] * Wcv[(size_t)j * cDH + d];
  }
  kc[co] = ak; vc[co] = av;
}

// ---------------- block compression, bf16 hi/lo (4 waves/block; n is block-uniform) --------
__global__ __launch_bounds__(256) void k_compress4_bf(
    const float* __restrict__ kbuf, const float* __restrict__ vbuf,
    const float* __restrict__ pos_k, const float* __restrict__ pos_v,
    const float* __restrict__ Wck, const float* __restrict__ Wcv,
    const float* __restrict__ mem_k, const float* __restrict__ mem_v,
    u16* __restrict__ kch, u16* __restrict__ kcl,
    u16* __restrict__ vth, u16* __restrict__ vtl)
{
  int wave = threadIdx.x >> 6, d = threadIdx.x & 63;
  int idx = blockIdx.x * 4 + wave;  // 4-aligned chunks never straddle the h=16 boundary,
  int h = idx % cH;                 // so n (and b) are block-uniform.
  int n = (idx / cH) % cNBLK;
  int b = idx / (cH * cNBLK);
  float ak, av;
  if (n == 0) {
    ak = mem_k[h * cDH + d];
    av = mem_v[h * cDH + d];
    size_t vr = ((size_t)(b * cH + h) * cDH + d) * cNP;
    for (int p = cNBLK; p < cNP; p++) { vth[vr + p] = 0; vtl[vr + p] = 0; }
  } else {
    __shared__ float kb[4][cBS * cDH], vb[4][cBS * cDH];
    int nb = n - 1;
    for (int t = d; t < cBS * cDH; t += 64) {
      int i = t >> 6, e = t & 63;
      size_t src = (((size_t)b * cS + nb * cBS + i) * cH + h) * cDH + e;
      kb[wave][t] = kbuf[src] + pos_k[(h * cBS + i) * cDH + e];
      vb[wave][t] = vbuf[src] + pos_v[(h * cBS + i) * cDH + e];
    }
    __syncthreads(); // block-uniform branch
    ak = 0.f; av = 0.f;
    #pragma unroll 4
    for (int j = 0; j < cBS * cDH; ++j) {
      ak += kb[wave][j] * Wck[(size_t)j * cDH + d];
      av += vb[wave][j] * Wcv[(size_t)j * cDH + d];
    }
  }
  u16 kh, kl, vh, vl;
  split_bf(ak, kh, kl); split_bf(av, vh, vl);
  size_t kco = ((size_t)(b * cH + h) * cNP + n) * cDH + d;
  kch[kco] = kh; kcl[kco] = kl;
  size_t vco = ((size_t)(b * cH + h) * cDH + d) * cNP + n;
  vth[vco] = vh; vtl[vco] = vl;
}

// ---- cattn helpers ----
__device__ __forceinline__ void top4_insert(float sv, int bi,
    float& v0, float& v1, float& v2, float& v3, int& i0, int& i1, int& i2, int& i3)
{
  if (sv > v3) {
    if (sv > v0)      { v3=v2;i3=i2; v2=v1;i2=i1; v1=v0;i1=i0; v0=sv;i0=bi; }
    else if (sv > v1) { v3=v2;i3=i2; v2=v1;i2=i1; v1=sv;i1=bi; }
    else if (sv > v2) { v3=v2;i3=i2; v2=sv;i2=bi; }
    else              { v3=sv;i3=bi; }
  }
}

// insert with tie-break (equal value -> lower block index wins)
__device__ __forceinline__ void top4_ins_tie(float sv, int bi,
    float& v0, float& v1, float& v2, float& v3, int& i0, int& i1, int& i2, int& i3)
{
  bool b3 = (sv > v3) || (sv == v3 && bi < i3);
  if (!b3) return;
  bool b0 = (sv > v0) || (sv == v0 && bi < i0);
  bool b1 = (sv > v1) || (sv == v1 && bi < i1);
  bool b2 = (sv > v2) || (sv == v2 && bi < i2);
  if (b0)      { v3=v2;i3=i2; v2=v1;i2=i1; v1=v0;i1=i0; v0=sv;i0=bi; }
  else if (b1) { v3=v2;i3=i2; v2=v1;i2=i1; v1=sv;i1=bi; }
  else if (b2) { v3=v2;i3=i2; v2=sv;i2=bi; }
  else         { v3=sv;i3=bi; }
}

// One pass over CNT columns (fallback scalar cattn helper)
template<int CNT>
__device__ __forceinline__ void cattn_cols(
    int base, int lane, int s_row, const float* __restrict__ kcb,
    const float* __restrict__ qrow, u16* __restrict__ ssb, float& lm,
    float& v0, float& v1, float& v2, float& v3,
    int& i0, int& i1, int& i2, int& i3)
{
  float sreg[CNT];
  #pragma unroll
  for (int u = 0; u < CNT; u++) sreg[u] = 0.f;
  #pragma unroll
  for (int d0 = 0; d0 < 4; d0++) {
    float4 qc0 = ((const float4*)qrow)[d0 * 4 + 0];
    float4 qc1 = ((const float4*)qrow)[d0 * 4 + 1];
    float4 qc2 = ((const float4*)qrow)[d0 * 4 + 2];
    float4 qc3 = ((const float4*)qrow)[d0 * 4 + 3];
    #pragma unroll
    for (int u = 0; u < CNT; u++) {
      int n = base + u;
      if (n < cNBLK) {
        const float4* kp = (const float4*)(kcb + (size_t)n * (cH * cDH) + d0 * 16);
        float4 k0 = kp[0], k1 = kp[1], k2 = kp[2], k3 = kp[3];
        sreg[u] += qc0.x*k0.x + qc0.y*k0.y + qc0.z*k0.z + qc0.w*k0.w
                 + qc1.x*k1.x + qc1.y*k1.y + qc1.z*k1.z + qc1.w*k1.w
                 + qc2.x*k2.x + qc2.y*k2.y + qc2.z*k2.z + qc2.w*k2.w
                 + qc3.x*k3.x + qc3.y*k3.y + qc3.z*k3.z + qc3.w*k3.w;
      }
    }
  }
  #pragma unroll
  for (int u = 0; u < CNT; u++) {
    int n = base + u;
    if (n >= cNBLK) continue;
    float a = sreg[u] * cSCALE;
    bool vis = (n == 0) || ((n - 1) * cBS + (cBS - 1) <= s_row);
    float sv = vis ? a : -INFINITY;
    ssb[lane * cSSTR + n] = f2b(sv);
    lm = fmaxf(lm, sv);
    if (n >= 1) top4_insert(sv, n - 1, v0, v1, v2, v3, i0, i1, i2, i3);
  }
}

// ---------------- scalar compressed attention (fallback path only) ----------------
__global__ __launch_bounds__(512, 4) void k_cattn_tile(
    const float* __restrict__ q, const float* __restrict__ kc, const float* __restrict__ vc,
    float* __restrict__ cout, float* __restrict__ sel_val, int* __restrict__ sel_idx)
{
  constexpr int NW = 8;
  constexpr int NCH = 33;
  __shared__ u16  ssb[64 * cSSTR];
  __shared__ float lmax[NW][64];
  __shared__ float lsum[NW][64];
  __shared__ float t4v[NW][64][4];
  __shared__ int   t4i[NW][64][4];
  __shared__ float mxs[64];
  __shared__ float invs[64];

  int tile = blockIdx.x & 15;
  int h = (blockIdx.x >> 4) & 15;
  int b = blockIdx.x >> 8;
  int s0 = tile * 64;
  int t = threadIdx.x;
  int lane = t & 63, wave = t >> 6;

  const float* kcb = kc + ((size_t)b * cNBLK * cH + h) * cDH;
  const float* vcb = vc + ((size_t)b * cNBLK * cH + h) * cDH;
  const int nstride = cH * cDH;

  {
    int r = lane;
    int s_row = s0 + r;
    const float* qrow = q + (((size_t)b * cS + s_row) * cH + h) * cDH;
    float v0=-INFINITY,v1=-INFINITY,v2=-INFINITY,v3=-INFINITY;
    int i0=0,i1=0,i2=0,i3=0;
    float lm = -INFINITY;
    int nb0 = wave * NCH;
    cattn_cols<11>(nb0,      r, s_row, kcb, qrow, ssb, lm, v0,v1,v2,v3, i0,i1,i2,i3);
    cattn_cols<11>(nb0 + 11, r, s_row, kcb, qrow, ssb, lm, v0,v1,v2,v3, i0,i1,i2,i3);
    cattn_cols<11>(nb0 + 22, r, s_row, kcb, qrow, ssb, lm, v0,v1,v2,v3, i0,i1,i2,i3);
    lmax[wave][lane] = lm;
    t4v[wave][lane][0]=v0; t4v[wave][lane][1]=v1; t4v[wave][lane][2]=v2; t4v[wave][lane][3]=v3;
    t4i[wave][lane][0]=i0; t4i[wave][lane][1]=i1; t4i[wave][lane][2]=i2; t4i[wave][lane][3]=i3;
  }
  __syncthreads();

  if (wave == 0) {
    int r = lane;
    float mx = -INFINITY;
    #pragma unroll
    for (int c = 0; c < NW; c++) mx = fmaxf(mx, lmax[c][r]);
    mxs[r] = mx;
    float v0=-INFINITY,v1=-INFINITY,v2=-INFINITY,v3=-INFINITY;
    int i0=0,i1=0,i2=0,i3=0;
    #pragma unroll
    for (int c = 0; c < NW; c++)
      #pragma unroll
      for (int u = 0; u < 4; u++)
        top4_insert(t4v[c][r][u], t4i[c][r][u], v0, v1, v2, v3, i0, i1, i2, i3);
    t4v[0][r][0]=v0; t4v[0][r][1]=v1; t4v[0][r][2]=v2; t4v[0][r][3]=v3;
    t4i[0][r][0]=i0; t4i[0][r][1]=i1; t4i[0][r][2]=i2; t4i[0][r][3]=i3;
  }
  __syncthreads();

  {
    int r = lane;
    float mx = mxs[r];
    float s = 0.f;
    int nb0 = wave * NCH;
    int nb1 = min(cNBLK, nb0 + NCH);
    for (int n = nb0; n < nb1; n++) {
      float sv = b2f(ssb[r * cSSTR + n]);
      float e = expf(sv - mx);
      ssb[r * cSSTR + n] = f2b(e);
      s += e;
    }
    lsum[wave][r] = s;
  }
  __syncthreads();

  if (wave == 0) {
    int r = lane;
    float sum = 0.f;
    #pragma unroll
    for (int c = 0; c < NW; c++) sum += lsum[c][r];
    float inv = 1.f / sum;
    invs[r] = inv;
    float mx = mxs[r];
    size_t so = (((size_t)b * cH + h) * cS + (s0 + r)) * cNSEL;
    #pragma unroll
    for (int u = 0; u < 4; u++) {
      sel_val[so + u] = expf(t4v[0][r][u] - mx) * inv;
      sel_idx[so + u] = t4i[0][r][u];
    }
  }
  __syncthreads();

  {
    int r = t >> 3, dq = t & 7;
    float4 a0 = {0,0,0,0}, a1 = {0,0,0,0};
    const u16* erow = ssb + r * cSSTR;
    const float* vbase = vcb + dq * 8;
#define ACC8(ee, w0, w1) \
    a0.x += (ee)*(w0).x; a0.y += (ee)*(w0).y; a0.z += (ee)*(w0).z; a0.w += (ee)*(w0).w; \
    a1.x += (ee)*(w1).x; a1.y += (ee)*(w1).y; a1.z += (ee)*(w1).z; a1.w += (ee)*(w1).w;
    for (int n = 0; n < 256; n += 4) {
      float e0 = b2f(erow[n+0]), e1 = b2f(erow[n+1]);
      float e2 = b2f(erow[n+2]), e3 = b2f(erow[n+3]);
      const float4* p0 = (const float4*)(vbase + (size_t)(n+0) * nstride);
      const float4* p1 = (const float4*)(vbase + (size_t)(n+1) * nstride);
      const float4* p2 = (const float4*)(vbase + (size_t)(n+2) * nstride);
      const float4* p3 = (const float4*)(vbase + (size_t)(n+3) * nstride);
      float4 w00 = p0[0], w01 = p0[1];
      float4 w10 = p1[0], w11 = p1[1];
      float4 w20 = p2[0], w21 = p2[1];
      float4 w30 = p3[0], w31 = p3[1];
      ACC8(e0, w00, w01)
      ACC8(e1, w10, w11)
      ACC8(e2, w20, w21)
      ACC8(e3, w30, w31)
    }
    {
      float e0 = b2f(erow[256]);
      const float4* p0 = (const float4*)(vbase + (size_t)256 * nstride);
      float4 w00 = p0[0], w01 = p0[1];
      ACC8(e0, w00, w01)
    }
#undef ACC8
    float inv = invs[r];
    float* crow = cout + (((size_t)b * cS + s0 + r) * cH + h) * cDH + dq * 8;
    ((float4*)crow)[0] = make_float4(a0.x*inv, a0.y*inv, a0.z*inv, a0.w*inv);
    ((float4*)crow)[1] = make_float4(a1.x*inv, a1.y*inv, a1.z*inv, a1.w*inv);
  }
}

// ---------------- MFMA compressed attention v4: LDS-staged kc/vt, async prefetch -----------
// Same math/operands/order as v3 (bitwise-identical output). Changes are pure data motion:
// kc staged to LDS once per block in 2 halves (4 waves shared; was 4x redundant global),
// vt staged in 2 halves with half-0 issued BEFORE softmax (latency hidden under VALU).
// kc LDS: linear chunk dest + XOR-swizzled source granule; reads swizzled -> conflict-free.
// vt LDS: [n-granule][d-row] layout -> linear dest, 2-way banks (free).
__global__ __launch_bounds__(256) void k_cattn_mfma(
    const u16* __restrict__ qbh, const u16* __restrict__ qbl,
    const u16* __restrict__ kch, const u16* __restrict__ kcl,
    const u16* __restrict__ vth, const u16* __restrict__ vtl,
    float* __restrict__ cout, float* __restrict__ sel_val, int* __restrict__ sel_idx)
{
  constexpr int SSTW = 296; // u16 stride per s-row in the e buffer
  __shared__ u16 kbuf[20480];        // 40.96KB: kc half (36.9KB used) / vt half (40.96KB)
  __shared__ u16 sws[4 * 16 * SSTW]; // 37.9KB raw-score/e buffer

  int tid = threadIdx.x;
  int bid = (blockIdx.x & 7) * 64 + (blockIdx.x >> 3); // XCD-bijective (512 = 8*64)
  int lane = tid & 63, w = tid >> 6;
  int l16 = lane & 15, rg = lane >> 4, g8 = rg << 3;
  int tile = (bid & 15) * 4 + w;  // 16-row tile in [0,64)
  int h = (bid >> 4) & 15, b = bid >> 8;
  int s0 = tile * 16;
  u16* sraw = sws + w * 16 * SSTW;

  // B-frag: q row s = s0 + l16 (pre-rope split-bf16)
  size_t qrow = (((size_t)b * cS + (s0 + l16)) * cH + h) * cDH;
  bf16x8 qh0 = *(const bf16x8*)(qbh + qrow + g8);
  bf16x8 qh1 = *(const bf16x8*)(qbh + qrow + 32 + g8);
  bf16x8 ql0 = *(const bf16x8*)(qbl + qrow + g8);
  bf16x8 ql1 = *(const bf16x8*)(qbl + qrow + 32 + g8);

  const u16* kchb = kch + (size_t)(b * cH + h) * cNP * cDH;
  const u16* kclb = kcl + (size_t)(b * cH + h) * cNP * cDH;
  const u16* vthb = vth + (size_t)(b * cH + h) * cDH * cNP;
  const u16* vtlb = vtl + (size_t)(b * cH + h) * cDH * cNP;

  float v0=-INFINITY, v1=-INFINITY, v2=-INFINITY, v3=-INFINITY;
  int i0=0, i1=0, i2=0, i3=0;
  float lm = -INFINITY;

  // ---- scores in 2 halves; kc staged to LDS once per block ----
  #pragma unroll
  for (int half = 0; half < 2; half++) {
    // stage: LDS rows 0..143 = kch (n = half*144 + r), rows 144..287 = kcl. 8 granules/row;
    // dest is chunk-linear (gload_lds requires it); source granule = (c&7) ^ (row&7).
    for (int c = tid; c < 2304; c += 256) {
      int rr = c >> 3, G = (c & 7) ^ (rr & 7);
      const u16* src = (rr < 144)
          ? kchb + (size_t)(half * 144 + rr) * cDH + (G << 3)
          : kclb + (size_t)(half * 144 + rr - 144) * cDH + (G << 3);
      gload16(kbuf + c * 8, src);
    }
    __syncthreads(); // stage complete (vmcnt drained)
    for (int ntl = 0; ntl < 9; ntl++) {
      int nt = half * 9 + ntl;
      int r = ntl * 16 + l16; // local hi row; lo at +144 ((144+r)&7 == r&7)
      int sw0 = ((rg ^ (r & 7)) << 3);
      int sw1 = (((rg + 4) ^ (r & 7)) << 3);
      bf16x8 kh0 = *(const bf16x8*)&kbuf[r * 64 + sw0];
      bf16x8 kh1 = *(const bf16x8*)&kbuf[r * 64 + sw1];
      bf16x8 kl0 = *(const bf16x8*)&kbuf[(144 + r) * 64 + sw0];
      bf16x8 kl1 = *(const bf16x8*)&kbuf[(144 + r) * 64 + sw1];
      f32x4 acc = (f32x4){0.f, 0.f, 0.f, 0.f};
      acc = __builtin_amdgcn_mfma_f32_16x16x32_bf16(kh0, qh0, acc, 0, 0, 0);
      acc = __builtin_amdgcn_mfma_f32_16x16x32_bf16(kh1, qh1, acc, 0, 0, 0);
      acc = __builtin_amdgcn_mfma_f32_16x16x32_bf16(kh0, ql0, acc, 0, 0, 0);
      acc = __builtin_amdgcn_mfma_f32_16x16x32_bf16(kh1, ql1, acc, 0, 0, 0);
      acc = __builtin_amdgcn_mfma_f32_16x16x32_bf16(kl0, qh0, acc, 0, 0, 0);
      acc = __builtin_amdgcn_mfma_f32_16x16x32_bf16(kl1, qh1, acc, 0, 0, 0);
      acc = __builtin_amdgcn_mfma_f32_16x16x32_bf16(kl0, ql0, acc, 0, 0, 0);
      acc = __builtin_amdgcn_mfma_f32_16x16x32_bf16(kl1, ql1, acc, 0, 0, 0);
      // D: col = l16 -> s-row; row = rg*4+j -> n
      u16 sb[4];
      #pragma unroll
      for (int j = 0; j < 4; j++) {
        int n = nt * 16 + rg * 4 + j;
        float a = acc[j] * cSCALE;
        bool vis = (n < cNBLK) && ((n == 0) || ((n - 1) * cBS + (cBS - 1) <= s0 + l16));
        float sv = vis ? a : -INFINITY;
        sb[j] = f2b(sv);
        lm = fmaxf(lm, sv);
        if (n >= 1) top4_ins_tie(sv, n - 1, v0, v1, v2, v3, i0, i1, i2, i3);
      }
      int cw = nt * 16 + rg * 4;
      *(u32*)&sraw[l16 * SSTW + cw]     = (u32)sb[0] | ((u32)sb[1] << 16);
      *(u32*)&sraw[l16 * SSTW + cw + 2] = (u32)sb[2] | ((u32)sb[3] << 16);
    }
    __syncthreads(); // all waves done reading kbuf before restage / reuse
  }

  // ---- issue vt half-0 staging now; softmax below hides its latency ----
  // LDS layout: [ngr 0..19][drow 0..127] 16B chunks; drow<64 = vth row d, else vtl row d-64.
  for (int c = tid; c < 2560; c += 256) {
    int ngr = c >> 7, drow = c & 127;
    const u16* src = (drow < 64)
        ? vthb + (size_t)drow * cNP + (ngr << 3)
        : vtlb + (size_t)(drow - 64) * cNP + (ngr << 3);
    gload16(kbuf + c * 8, src);
  }

  // ---- merge across the 4 rg-replicas of each s-row (lanes xor 16, 32) ----
  #pragma unroll
  for (int o = 16; o < 64; o <<= 1) {
    lm = fmaxf(lm, __shfl_xor(lm, o));
    float p0 = __shfl_xor(v0, o), p1 = __shfl_xor(v1, o);
    float p2 = __shfl_xor(v2, o), p3 = __shfl_xor(v3, o);
    int   q0 = __shfl_xor(i0, o), q1 = __shfl_xor(i1, o);
    int   q2 = __shfl_xor(i2, o), q3 = __shfl_xor(i3, o);
    top4_ins_tie(p0, q0, v0, v1, v2, v3, i0, i1, i2, i3);
    top4_ins_tie(p1, q1, v0, v1, v2, v3, i0, i1, i2, i3);
    top4_ins_tie(p2, q2, v0, v1, v2, v3, i0, i1, i2, i3);
    top4_ins_tie(p3, q3, v0, v1, v2, v3, i0, i1, i2, i3);
  }

  // ---- exp + sum over this lane's 72 owned values; e overwrites sws ----
  float sum = 0.f;
  for (int nt = 0; nt < 18; nt++) {
    int cw = nt * 16 + rg * 4;
    u32 w01 = *(u32*)&sraw[l16 * SSTW + cw];
    u32 w23 = *(u32*)&sraw[l16 * SSTW + cw + 2];
    float e0 = expf(b2f((u16)(w01 & 0xffff)) - lm);
    float e1 = expf(b2f((u16)(w01 >> 16)) - lm);
    float e2 = expf(b2f((u16)(w23 & 0xffff)) - lm);
    float e3 = expf(b2f((u16)(w23 >> 16)) - lm);
    sum += (e0 + e1) + (e2 + e3);
    *(u32*)&sraw[l16 * SSTW + cw]     = (u32)f2b(e0) | ((u32)f2b(e1) << 16);
    *(u32*)&sraw[l16 * SSTW + cw + 2] = (u32)f2b(e2) | ((u32)f2b(e3) << 16);
  }
  #pragma unroll
  for (int o = 16; o < 64; o <<= 1) sum += __shfl_xor(sum, o);
  float inv = 1.f / sum;

  if (rg == 0) {
    size_t so = (((size_t)b * cH + h) * cS + (s0 + l16)) * cNSEL;
    sel_val[so + 0] = expf(v0 - lm) * inv; sel_idx[so + 0] = i0;
    sel_val[so + 1] = expf(v1 - lm) * inv; sel_idx[so + 1] = i1;
    sel_val[so + 2] = expf(v2 - lm) * inv; sel_idx[so + 2] = i2;
    sel_val[so + 3] = expf(v3 - lm) * inv; sel_idx[so + 3] = i3;
  }
  __syncthreads(); // vt h0 staged + e visible across lanes

  // ---- PV: out^T = mfma(vc^T, e), K = 288 in 2 staged halves (n 0..159, 160..287) ----
  f32x4 pacc[4];
  #pragma unroll
  for (int dt = 0; dt < 4; dt++) pacc[dt] = (f32x4){0.f, 0.f, 0.f, 0.f};
  for (int kc9 = 0; kc9 < 5; kc9++) {
    bf16x8 ef = *(const bf16x8*)&sraw[l16 * SSTW + kc9 * 32 + g8];
    int ngr = kc9 * 4 + rg;
    #pragma unroll
    for (int dt = 0; dt < 4; dt++) {
      bf16x8 vh = *(const bf16x8*)&kbuf[(ngr * 128 + dt * 16 + l16) * 8];
      bf16x8 vl = *(const bf16x8*)&kbuf[(ngr * 128 + 64 + dt * 16 + l16) * 8];
      pacc[dt] = __builtin_amdgcn_mfma_f32_16x16x32_bf16(vh, ef, pacc[dt], 0, 0, 0);
      pacc[dt] = __builtin_amdgcn_mfma_f32_16x16x32_bf16(vl, ef, pacc[dt], 0, 0, 0);
    }
  }
  __syncthreads(); // done reading vt h0
  for (int c = tid; c < 2048; c += 256) { // vt h1: 16 n-granules (n 160..287)
    int ngr = c >> 7, drow = c & 127;
    const u16* src = (drow < 64)
        ? vthb + (size_t)drow * cNP + 160 + (ngr << 3)
        : vtlb + (size_t)(drow - 64) * cNP + 160 + (ngr << 3);
    gload16(kbuf + c * 8, src);
  }
  __syncthreads(); // vt h1 staged
  for (int kc9 = 5; kc9 < 9; kc9++) {
    bf16x8 ef = *(const bf16x8*)&sraw[l16 * SSTW + kc9 * 32 + g8];
    int ngr = (kc9 - 5) * 4 + rg;
    #pragma unroll
    for (int dt = 0; dt < 4; dt++) {
      bf16x8 vh = *(const bf16x8*)&kbuf[(ngr * 128 + dt * 16 + l16) * 8];
      bf16x8 vl = *(const bf16x8*)&kbuf[(ngr * 128 + 64 + dt * 16 + l16) * 8];
      pacc[dt] = __builtin_amdgcn_mfma_f32_16x16x32_bf16(vh, ef, pacc[dt], 0, 0, 0);
      pacc[dt] = __builtin_amdgcn_mfma_f32_16x16x32_bf16(vl, ef, pacc[dt], 0, 0, 0);
    }
  }
  // D: col = l16 -> s; row = rg*4+j -> d = dt*16 + rg*4 + j (j consecutive -> float4)
  float* crow = cout + (((size_t)b * cS + (s0 + l16)) * cH + h) * cDH;
  #pragma unroll
  for (int dt = 0; dt < 4; dt++) {
    *(float4*)(crow + dt * 16 + rg * 4) =
        make_float4(pacc[dt][0] * inv, pacc[dt][1] * inv,
                    pacc[dt][2] * inv, pacc[dt][3] * inv);
  }
}

// ---------------- in-place RoPE on q and k ----------------
__global__ __launch_bounds__(256) void k_rope(float* __restrict__ q, float* __restrict__ k)
{
  int t = blockIdx.x * 256 + threadIdx.x;
  int j = t & 31; int h = (t >> 5) & (cH - 1); int bs = t >> 9;
  int s = bs & (cS - 1);
  float inv = expf(-(float)j * 0.28782313662425575f);
  float ang = (float)s * inv;
  float sn, c; sincosf(ang, &sn, &c);
  size_t base = ((size_t)bs * cH + h) * cDH;
  float q1 = q[base + j], q2 = q[base + j + 32];
  q[base + j]      = q1 * c - q2 * sn;
  q[base + j + 32] = q1 * sn + q2 * c;
  float k1 = k[base + j], k2 = k[base + j + 32];
  k[base + j]      = k1 * c - k2 * sn;
  k[base + j + 32] = k1 * sn + k2 * c;
}

// ---------------- fused fine + sliding-window attention ----------------
__global__ __launch_bounds__(256) void k_fsattn(
    const float* __restrict__ qr, const float* __restrict__ kr, const float* __restrict__ v,
    const float* __restrict__ sel_val, const int* __restrict__ sel_idx,
    float* __restrict__ fout, float* __restrict__ sout)
{
  int wave = threadIdx.x >> 6, lane = threadIdx.x & 63;
  int sidx = blockIdx.x * 4 + wave;
  int s = sidx % cS; int h = (sidx / cS) % cH; int b = sidx / (cS * cH);
  __shared__ float qs[4][cDH];
  __shared__ float pf[4][20];
  __shared__ float ps[4][cWIN];
  __shared__ int blk[4][5];
  __shared__ int bok[4][5];
  size_t qoff = (((size_t)b * cS + s) * cH + h) * cDH;
  qs[wave][lane] = qr[qoff + lane];
  if (lane < 5) {
    size_t so = (((size_t)b * cH + h) * cS + s) * cNSEL;
    if (lane < 4) { blk[wave][lane] = sel_idx[so + lane]; bok[wave][lane] = sel_val[so + lane] > 0.f; }
    else          { blk[wave][4] = s / cBS; bok[wave][4] = 1; }
  }
  __syncthreads();

  const float* kp = nullptr;
  if (lane < 20) {
    int tt = lane >> 2, i = lane & 3;
    int kpos = blk[wave][tt] * cBS + i;
    if (bok[wave][tt] && kpos <= s)
      kp = kr + (((size_t)b * cS + kpos) * cH + h) * cDH;
  } else if (lane >= 32) {
    int sp = s - (lane - 32);
    if (sp >= 0)
      kp = kr + (((size_t)b * cS + sp) * cH + h) * cDH;
  }
  float sc = -INFINITY;
  if (kp) {
    float a = 0.f;
    #pragma unroll 16
    for (int e = 0; e < cDH; e++) a += qs[wave][e] * kp[e];
    sc = a * cSCALE;
  }
  float mx = sc;
  #pragma unroll
  for (int o = 16; o; o >>= 1) mx = fmaxf(mx, __shfl_xor(mx, o, 32));
  float ex = (sc == -INFINITY) ? 0.f : expf(sc - mx);
  float sum = ex;
  #pragma unroll
  for (int o = 16; o; o >>= 1) sum += __shfl_xor(sum, o, 32);
  float pp = ex / sum;
  if (lane < 20) pf[wave][lane] = pp;
  if (lane >= 32) ps[wave][lane - 32] = pp;
  __syncthreads();

  float accf = 0.f;
  for (int tt = 0; tt < 5; tt++) {
    if (!bok[wave][tt]) continue;
    int kbase = blk[wave][tt] * cBS;
    #pragma unroll
    for (int i = 0; i < cBS; i++) {
      float pm = pf[wave][tt * cBS + i];
      if (pm != 0.f)
        accf += pm * v[(((size_t)b * cS + kbase + i) * cH + h) * cDH + lane];
    }
  }
  float accs = 0.f;
  int wm = min(cWIN, s + 1);
  for (int w = 0; w < wm; w++)
    accs += ps[wave][w] * v[(((size_t)b * cS + s - w) * cH + h) * cDH + lane];
  fout[qoff + lane] = accf;
  sout[qoff + lane] = accs;
}

// ---------------- gated combine (f32 out, fallback) ----------------
__global__ __launch_bounds__(256) void k_combine(
    const float* __restrict__ gpre, const float* __restrict__ cout,
    const float* __restrict__ fout, const float* __restrict__ sout, float* __restrict__ o)
{
  int t = blockIdx.x * 256 + threadIdx.x;
  int hh = (t >> 6) & 15; int bs = t >> 10;
  float g0 = sigf(gpre[(size_t)bs * 48 + hh * 3 + 0]);
  float g1 = sigf(gpre[(size_t)bs * 48 + hh * 3 + 1]);
  float g2 = sigf(gpre[(size_t)bs * 48 + hh * 3 + 2]);
  o[t] = g0 * cout[t] + g1 * fout[t] + g2 * sout[t];
}

// ---------------- gated combine -> bf16 hi/lo (feeds Wo MFMA GEMM) ----------------
__global__ __launch_bounds__(256) void k_combine_bf(
    const float* __restrict__ gpre, const float* __restrict__ cout,
    const float* __restrict__ fout, const float* __restrict__ sout,
    u16* __restrict__ oh, u16* __restrict__ ol)
{
  int t = blockIdx.x * 256 + threadIdx.x;
  int hh = (t >> 6) & 15; int bs = t >> 10;
  float g0 = sigf(gpre[(size_t)bs * 48 + hh * 3 + 0]);
  float g1 = sigf(gpre[(size_t)bs * 48 + hh * 3 + 1]);
  float g2 = sigf(gpre[(size_t)bs * 48 + hh * 3 + 2]);
  float v = g0 * cout[t] + g1 * fout[t] + g2 * sout[t];
  u16 hb, lb; split_bf(v, hb, lb);
  oh[t] = hb; ol[t] = lb;
}

extern "C" void kernel_launch(void* const* d_in, const int* in_sizes, int n_in,
                              void* d_out, int out_size, void* d_ws, size_t ws_size,
                              hipStream_t stream) {
  float* out = (float*)d_out;

  static const int exp_sizes[17] = {
    2097152, 2097152, 2097152, 2,
    1048576, 1048576, 1048576,
    4096, 4096,
    16384, 16384,
    1024, 1024,
    49152, 1048576, 4194304, 4194304
  };
  if (n_in < 17) {
    k_fill<<<dim3(8192), dim3(256), 0, stream>>>(out, 500.0f + 10.0f * n_in);
    return;
  }
  for (int i = 0; i < 17; ++i) {
    if (in_sizes[i] != exp_sizes[i] && in_sizes[i] != 4 * exp_sizes[i]) {
      k_fill<<<dim3(8192), dim3(256), 0, stream>>>(out, 1000.0f + 50.0f * i);
      return;
    }
  }

  const float* x     = (const float*)d_in[0];
  const float* x0    = (const float*)d_in[2];
  const float* lam   = (const float*)d_in[3];
  const float* Wq    = (const float*)d_in[4];
  const float* Wk    = (const float*)d_in[5];
  const float* Wv    = (const float*)d_in[6];
  const float* pos_k = (const float*)d_in[7];
  const float* pos_v = (const float*)d_in[8];
  const float* Wck   = (const float*)d_in[9];
  const float* Wcv   = (const float*)d_in[10];
  const float* mem_k = (const float*)d_in[11];
  const float* mem_v = (const float*)d_in[12];
  const float* Wg    = (const float*)d_in[13];
  const float* Wo    = (const float*)d_in[14];
  const float* Wfc   = (const float*)d_in[15];
  const float* Wpr   = (const float*)d_in[16];

  float* ws = (float*)d_ws;
  const size_t E = (size_t)cM * cD; // 2097152
  float* gpre = ws;                                   // 98304
  float* selv = ws + 98304;                           // 131072
  int*   seli = (int*)(ws + 98304 + 131072);          // 131072
  // slack region: ws+360448 .. ws+1048576 — holds padded WgT (65536 floats)
  u16* WgTh = (u16*)(ws + 360448);
  u16* WgTl = WgTh + 65536;
  const size_t A0 = 1048576;
  float* xr = ws + A0 + 0 * E;
  float* h  = ws + A0 + 1 * E; // f32 h; later reused as m_bf (hi/lo) in mfma path
  float* q  = ws + A0 + 2 * E; // roped in place; later fc_bf hi
  float* k  = ws + A0 + 3 * E;
  float* v  = ws + A0 + 4 * E;
  float* co = ws + A0 + 5 * E; // cout
  float* fo = ws + A0 + 6 * E; // kc_bf/vt_bf first, then fout
  float* so = ws + A0 + 7 * E; // q_bf first, then sout
  float* x1 = ws + A0 + 8 * E;
  float* fc = ws + A0 + 2 * E; // fallback f32 fc alias over q,k,v,co
  float* kc = fo;              // fallback f32 kc/vc aliases
  float* vc = so;

  // ---- bf16 region (beyond the legacy 76MB layout) ----
  const size_t P = A0 + 9 * E; // 19,922,944 floats
  const size_t NEED_FLOATS = P + 14680064; // unchanged vs rounds 1-8
  bool use_mfma = (ws_size >= NEED_FLOATS * sizeof(float));

  u16* WvTh = (u16*)(ws + P);              u16* WvTl = WvTh + 1048576;
  u16* WoTh = (u16*)(ws + P + 1048576);    u16* WoTl = WoTh + 1048576;
  u16* WfcTh = (u16*)(ws + P + 2097152);   u16* WfcTl = WfcTh + 4194304;
  u16* WprTh = (u16*)(ws + P + 6291456);   u16* WprTl = WprTh + 4194304;
  u16* hbh = (u16*)(ws + P + 10485760);    u16* hbl = hbh + 2097152;
  u16* obh = (u16*)(ws + P + 12582912);    u16* obl = obh + 2097152;
  u16* mbh = (u16*)h;                      u16* mbl = mbh + 2097152;   // alias h (dead)
  u16* fbh = (u16*)q;                      u16* fbl = fbh + 8388608;   // alias q..co (dead)
  // WqT/WkT alias x1 (dead until the Wo GEMM overwrites it)
  u16* WqTh = (u16*)x1;                    u16* WqTl = WqTh + 1048576;
  u16* WkTh = WqTh + 2097152;              u16* WkTl = WqTh + 3145728;
  // cattn bf16 buffers alias fo/so (dead until fsattn writes fout/sout AFTER cattn)
  const size_t KCN = (size_t)cB * cH * cNP * cDH; // 589824 u16
  u16* kch = (u16*)fo;       u16* kcl = kch + KCN;
  u16* vth = kcl + KCN;      u16* vtl = vth + KCN;   // total 2.36M u16 < E floats
  u16* qbh = (u16*)so;       u16* qbl = qbh + 2097152; // 2x2M u16 = E floats exactly

  dim3 b256(256), b64(64), b512(512);
  dim3 gSq(cD / 64, cM / 64);

  if (use_mfma) {
    // one-time-per-launch weight transpose + hi/lo split
    k_wsplit_t<<<dim3(32, 32), b256, 0, stream>>>(Wq, WqTh, WqTl, 1024, 1024);
    k_wsplit_t<<<dim3(32, 32), b256, 0, stream>>>(Wk, WkTh, WkTl, 1024, 1024);
    k_wsplit_t<<<dim3(32, 32), b256, 0, stream>>>(Wv, WvTh, WvTl, 1024, 1024);
    k_wsplit_t<<<dim3(32, 32), b256, 0, stream>>>(Wo, WoTh, WoTl, 1024, 1024);
    k_wsplit_t<<<dim3(128, 32), b256, 0, stream>>>(Wfc, WfcTh, WfcTl, 1024, 4096);
    k_wsplit_t<<<dim3(32, 128), b256, 0, stream>>>(Wpr, WprTh, WprTl, 4096, 1024);
    k_wsplit_g<<<dim3(256), b256, 0, stream>>>(Wg, WgTh, WgTl);

    k_lerp_rmsnorm<<<dim3(cM), b256, 0, stream>>>(x, x0, lam, xr, h, hbh, hbl);

    // fused q|k|v|g GEMM (4-term split-bf16); q also emits pre-rope bf16 hi/lo
    k_mfma_qkvg<<<dim3(49, 32), b256, 0, stream>>>(
        hbh, hbl, WqTh, WqTl, WkTh, WkTl, WvTh, WvTl, WgTh, WgTl,
        q, k, v, gpre, qbh, qbl);

    k_compress4_bf<<<dim3(cB * cNBLK * cH / 4), b256, 0, stream>>>(
        k, v, pos_k, pos_v, Wck, Wcv, mem_k, mem_v, kch, kcl, vth, vtl);
    k_cattn_mfma<<<dim3(cB * cH * 16), b256, 0, stream>>>(
        qbh, qbl, kch, kcl, vth, vtl, co, selv, seli);
    k_rope<<<dim3(cB * cS * cH * 32 / 256), b256, 0, stream>>>(q, k);
    k_fsattn<<<dim3(cB * cH * cS / 4), b256, 0, stream>>>(q, k, v, selv, seli, fo, so);

    k_combine_bf<<<dim3((cM * cD) / 256), b256, 0, stream>>>(gpre, co, fo, so, obh, obl);

    // x1 = o @ Wo + xr  (overwrites the WqT/WkT alias region — dead now)
    k_mfma_gemm<64, 64, 0, 0, 3><<<dim3(cD / 64, cM / 64), b256, 0, stream>>>(
        obh, obl, WoTh, WoTl, xr, x1, nullptr, nullptr, cM, cD, cD);

    // m = rmsnorm(x1) -> bf16 hi/lo only (into dead h region)
    k_rmsnorm<<<dim3(cM), b256, 0, stream>>>(x1, nullptr, mbh, mbl);

    // fc = relu(m @ Wfc)^2 -> bf16 hi/lo directly (into dead q..co region)
    k_mfma_gemm<64, 128, 1, 1, 3><<<dim3(cDFF / 128, cM / 64), b256, 0, stream>>>(
        mbh, mbl, WfcTh, WfcTl, nullptr, nullptr, fbh, fbl, cM, cDFF, cD);

    // out = fc @ Wproj + x1
    k_mfma_gemm<64, 64, 0, 0, 3><<<dim3(cD / 64, cM / 64), b256, 0, stream>>>(
        fbh, fbl, WprTh, WprTl, x1, out, nullptr, nullptr, cM, cD, cDFF);
  } else {
    // fallback: all-fp32 path
    k_lerp_rmsnorm<<<dim3(cM), b256, 0, stream>>>(x, x0, lam, xr, h, nullptr, nullptr);
    k_gemm<0><<<gSq, b256, 0, stream>>>(h, Wq, nullptr, q, cM, cD, cD);
    k_gemm<0><<<gSq, b256, 0, stream>>>(h, Wk, nullptr, k, cM, cD, cD);
    k_gemm<0><<<gSq, b256, 0, stream>>>(h, Wv, nullptr, v, cM, cD, cD);
    k_gemm<0><<<dim3(1, cM / 64), b256, 0, stream>>>(h, Wg, nullptr, gpre, cM, 48, cD);
    k_compress4<<<dim3(cB * cNBLK * cH), b64, 0, stream>>>(k, v, pos_k, pos_v, Wck, Wcv,
                                                           mem_k, mem_v, kc, vc);
    k_cattn_tile<<<dim3(cB * cH * 16), b512, 0, stream>>>(q, kc, vc, co, selv, seli);
    k_rope<<<dim3(cB * cS * cH * 32 / 256), b256, 0, stream>>>(q, k);
    k_fsattn<<<dim3(cB * cH * cS / 4), b256, 0, stream>>>(q, k, v, selv, seli, fo, so);
    k_combine<<<dim3((cM * cD) / 256), b256, 0, stream>>>(gpre, co, fo, so, co);
    k_gemm<0><<<gSq, b256, 0, stream>>>(co, Wo, xr, x1, cM, cD, cD);
    k_rmsnorm<<<dim3(cM), b256, 0, stream>>>(x1, h, nullptr, nullptr);
    k_gemm<1><<<dim3(cDFF / 64, cM / 64), b256, 0, stream>>>(h, Wfc, nullptr, fc, cM, cDFF, cD);
    k_gemm<0><<<gSq, b256, 0, stream>>>(fc, Wpr, x1, out, cM, cD, cDFF);
  }
}

// Round 10
// 624.333 us; speedup vs baseline: 1.0137x; 1.0137x over previous
//
#include <hip/hip_runtime.h>

// Problem constants — NOTE: BS=4 (H, DH, BS, NSEL, WIN = 16, 64, 4, 4, 32)
constexpr int cH = 16, cDH = 64, cBS = 4, cNSEL = 4, cWIN = 32;
constexpr int cB = 2, cS = 1024, cD = 1024;
constexpr int cNB = 256, cNBLK = 257, cDFF = 4096, cM = 2048; // cM = B*S
constexpr float cSCALE = 0.125f; // DH^-0.5
constexpr int cSSTR = 258; // old scalar cattn ssb stride
constexpr int cNP = 288;   // padded compressed-block count

typedef unsigned short u16;
typedef unsigned int u32;
typedef __attribute__((ext_vector_type(8))) __bf16 bf16x8;
typedef __attribute__((ext_vector_type(8))) u16 u16x8;
typedef __attribute__((ext_vector_type(4))) float f32x4;
static_assert(sizeof(bf16x8) == 16, "bf16x8 must be 16B");

__device__ __forceinline__ float sigf(float x) { return 1.f / (1.f + expf(-x)); }
__device__ __forceinline__ float b2f(u16 u) {
  union { float f; u32 u; } c; c.u = ((u32)u) << 16; return c.f;
}
__device__ __forceinline__ u16 f2b(float f) {
  union { float f; u32 u; } c; c.f = f;
  u32 u = c.u;
  return (u16)((u + 0x7fffu + ((u >> 16) & 1u)) >> 16); // RNE
}
__device__ __forceinline__ void split_bf(float v, u16& h, u16& l) {
  h = f2b(v);
  l = f2b(v - b2f(h)); // exact residual, then RNE
}

// async global->LDS, 16B per lane; LDS dest must be wave-uniform base + lane*16
typedef const __attribute__((address_space(1))) void* gas_t;
typedef __attribute__((address_space(3))) void* las_t;
__device__ __forceinline__ void gload16(void* lds, const void* g) {
  __builtin_amdgcn_global_load_lds((gas_t)g, (las_t)lds, 16, 0, 0);
}

__global__ __launch_bounds__(256) void k_fill(float* __restrict__ p, float v)
{
  p[blockIdx.x * 256 + threadIdx.x] = v;
}

// ---------------- xr = l0*x + l1*x0 ; h = rmsnorm(xr) (+ optional bf16 hi/lo) ----------------
__global__ __launch_bounds__(256) void k_lerp_rmsnorm(
    const float* __restrict__ x, const float* __restrict__ x0,
    const float* __restrict__ lambdas, float* __restrict__ xr, float* __restrict__ h,
    u16* __restrict__ hbh, u16* __restrict__ hbl)
{
  int row = blockIdx.x, tid = threadIdx.x;
  float l0 = lambdas[0], l1 = lambdas[1];
  size_t base = (size_t)row * cD + tid * 4;
  float4 xa = *(const float4*)(x + base);
  float4 xb = *(const float4*)(x0 + base);
  float v0 = l0 * xa.x + l1 * xb.x;
  float v1 = l0 * xa.y + l1 * xb.y;
  float v2 = l0 * xa.z + l1 * xb.z;
  float v3 = l0 * xa.w + l1 * xb.w;
  float ss = v0*v0 + v1*v1 + v2*v2 + v3*v3;
  #pragma unroll
  for (int o = 32; o; o >>= 1) ss += __shfl_xor(ss, o);
  __shared__ float red[4];
  if ((tid & 63) == 0) red[tid >> 6] = ss;
  __syncthreads();
  float tot = red[0] + red[1] + red[2] + red[3];
  float sc = rsqrtf(tot * (1.0f / cD) + 1e-6f);
  *(float4*)(xr + base) = make_float4(v0, v1, v2, v3);
  float h0 = v0*sc, h1 = v1*sc, h2 = v2*sc, h3 = v3*sc;
  *(float4*)(h + base) = make_float4(h0, h1, h2, h3);
  if (hbh) {
    ushort4 hv, lv;
    split_bf(h0, hv.x, lv.x); split_bf(h1, hv.y, lv.y);
    split_bf(h2, hv.z, lv.z); split_bf(h3, hv.w, lv.w);
    *(ushort4*)(hbh + base) = hv;
    *(ushort4*)(hbl + base) = lv;
  }
}

// ---------------- rmsnorm: f32 out and/or bf16 hi/lo out ----------------
__global__ __launch_bounds__(256) void k_rmsnorm(
    const float* __restrict__ x, float* __restrict__ out,
    u16* __restrict__ obh, u16* __restrict__ obl)
{
  int row = blockIdx.x, tid = threadIdx.x;
  size_t base = (size_t)row * cD + tid * 4;
  float4 v = *(const float4*)(x + base);
  float ss = v.x*v.x + v.y*v.y + v.z*v.z + v.w*v.w;
  #pragma unroll
  for (int o = 32; o; o >>= 1) ss += __shfl_xor(ss, o);
  __shared__ float red[4];
  if ((tid & 63) == 0) red[tid >> 6] = ss;
  __syncthreads();
  float tot = red[0] + red[1] + red[2] + red[3];
  float sc = rsqrtf(tot * (1.0f / cD) + 1e-6f);
  float h0 = v.x*sc, h1 = v.y*sc, h2 = v.z*sc, h3 = v.w*sc;
  if (out) *(float4*)(out + base) = make_float4(h0, h1, h2, h3);
  if (obh) {
    ushort4 hv, lv;
    split_bf(h0, hv.x, lv.x); split_bf(h1, hv.y, lv.y);
    split_bf(h2, hv.z, lv.z); split_bf(h3, hv.w, lv.w);
    *(ushort4*)(obh + base) = hv;
    *(ushort4*)(obl + base) = lv;
  }
}

// ---------------- tiled f32 GEMM (fallback path only) ----------------
template<int EPI>
__global__ __launch_bounds__(256) void k_gemm(
    const float* __restrict__ A, const float* __restrict__ Bw,
    const float* __restrict__ R, float* __restrict__ C, int M, int N, int K)
{
  constexpr int BM = 64, BN = 64, BK = 16;
  __shared__ float As[BK][BM];
  __shared__ float Bs[BK][BN];
  int tid = threadIdx.x;
  int tx = tid & 15, ty = tid >> 4;
  int m0 = blockIdx.y * BM, n0 = blockIdx.x * BN;
  float acc[4][4] = {};
  for (int k0 = 0; k0 < K; k0 += BK) {
    {
      int r = tid >> 2, c4 = (tid & 3) << 2;
      float4 av = *(const float4*)(A + (size_t)(m0 + r) * K + k0 + c4);
      As[c4+0][r] = av.x; As[c4+1][r] = av.y; As[c4+2][r] = av.z; As[c4+3][r] = av.w;
    }
    {
      int kr = tid >> 4, c4 = (tid & 15) << 2;
      int n = n0 + c4;
      const float* bp = Bw + (size_t)(k0 + kr) * N;
      if (n + 3 < N) {
        float4 bv = *(const float4*)(bp + n);
        Bs[kr][c4+0] = bv.x; Bs[kr][c4+1] = bv.y; Bs[kr][c4+2] = bv.z; Bs[kr][c4+3] = bv.w;
      } else {
        #pragma unroll
        for (int j = 0; j < 4; j++) Bs[kr][c4+j] = (n + j < N) ? bp[n + j] : 0.f;
      }
    }
    __syncthreads();
    #pragma unroll
    for (int kk = 0; kk < BK; ++kk) {
      float4 a4 = *(const float4*)&As[kk][ty << 2];
      float4 b4 = *(const float4*)&Bs[kk][tx << 2];
      float av[4] = {a4.x, a4.y, a4.z, a4.w};
      float bv[4] = {b4.x, b4.y, b4.z, b4.w};
      #pragma unroll
      for (int i = 0; i < 4; i++)
        #pragma unroll
        for (int j = 0; j < 4; j++) acc[i][j] += av[i] * bv[j];
    }
    __syncthreads();
  }
  #pragma unroll
  for (int i = 0; i < 4; i++) {
    int m = m0 + (ty << 2) + i;
    #pragma unroll
    for (int j = 0; j < 4; j++) {
      int n = n0 + (tx << 2) + j;
      if (n < N) {
        float vv = acc[i][j];
        if (EPI == 1) vv = vv > 0.f ? vv * vv : 0.f;
        if (R) vv += R[(size_t)m * N + n];
        C[(size_t)m * N + n] = vv;
      }
    }
  }
}

// ---------------- weight transpose + bf16 hi/lo split: W(K,N) -> Th/Tl (N,K) ----------------
__global__ __launch_bounds__(256) void k_wsplit_t(
    const float* __restrict__ W, u16* __restrict__ Th, u16* __restrict__ Tl, int K, int N)
{
  __shared__ float tile[32][33];
  int n0 = blockIdx.x * 32, k0 = blockIdx.y * 32;
  int r = threadIdx.x >> 3, c4 = (threadIdx.x & 7) << 2;
  float4 v = *(const float4*)(W + (size_t)(k0 + r) * N + n0 + c4);
  tile[r][c4+0] = v.x; tile[r][c4+1] = v.y; tile[r][c4+2] = v.z; tile[r][c4+3] = v.w;
  __syncthreads();
  float f0 = tile[c4+0][r], f1 = tile[c4+1][r], f2 = tile[c4+2][r], f3 = tile[c4+3][r];
  ushort4 hv, lv;
  split_bf(f0, hv.x, lv.x); split_bf(f1, hv.y, lv.y);
  split_bf(f2, hv.z, lv.z); split_bf(f3, hv.w, lv.w);
  size_t ob = (size_t)(n0 + r) * K + k0 + c4;
  *(ushort4*)(Th + ob) = hv;
  *(ushort4*)(Tl + ob) = lv;
}

// ---------------- Wg (1024,48) -> padded transpose (64,1024) bf16 hi/lo ----------------
__global__ __launch_bounds__(256) void k_wsplit_g(
    const float* __restrict__ W, u16* __restrict__ Th, u16* __restrict__ Tl)
{
  int idx = blockIdx.x * 256 + threadIdx.x; // < 65536
  int n = idx >> 10, kk = idx & 1023;
  float v = (n < 48) ? W[(size_t)kk * 48 + n] : 0.f;
  u16 hb, lb; split_bf(v, hb, lb);
  Th[idx] = hb; Tl[idx] = lb;
}

// ---------------- split-bf16 MFMA GEMM v2: BK=64, XOR-swizzled LDS, XCD swizzle ------------
// Supports BM=32 (MR=1) for high-grid-count variants of narrow GEMMs.
template<int BM, int BN, int EPI, int OUTBF, int TERMS>
__global__ __launch_bounds__(256) void k_mfma_gemm(
    const u16* __restrict__ Ah_g, const u16* __restrict__ Al_g,
    const u16* __restrict__ Bh_g, const u16* __restrict__ Bl_g,
    const float* __restrict__ R, float* __restrict__ Cf,
    u16* __restrict__ Ch, u16* __restrict__ Cl,
    int M, int N, int K)
{
  constexpr int BK = 64;
  constexpr int MR = BM / 32, NR = BN / 32;
  __shared__ u16 lds[(BM + BN) * BK * 2];
  u16* Ah = lds;
  u16* Al = Ah + BM * BK;
  u16* Bh = Al + BM * BK;
  u16* Bl = Bh + BN * BK;

  int tid = threadIdx.x;
  int lane = tid & 63, wave = tid >> 6;
  int wr = wave >> 1, wc = wave & 1;
  int l16 = lane & 15, rg = lane >> 4;

  int nwg = gridDim.x * gridDim.y;
  int lin = blockIdx.y * gridDim.x + blockIdx.x;
  if ((nwg & 7) == 0) lin = (lin & 7) * (nwg >> 3) + (lin >> 3);
  int m0 = (lin / gridDim.x) * BM, n0 = (lin % gridDim.x) * BN;

  f32x4 acc[MR][NR];
  #pragma unroll
  for (int m = 0; m < MR; m++)
    #pragma unroll
    for (int n = 0; n < NR; n++) acc[m][n] = (f32x4){0.f, 0.f, 0.f, 0.f};

  for (int k0 = 0; k0 < K; k0 += BK) {
    #pragma unroll
    for (int c = tid; c < BM * 8; c += 256) {
      int row = c >> 3, gs = (c & 7) ^ (row & 7);
      size_t off = (size_t)(m0 + row) * K + k0 + (gs << 3);
      gload16(Ah + c * 8, Ah_g + off);
      gload16(Al + c * 8, Al_g + off);
    }
    #pragma unroll
    for (int c = tid; c < BN * 8; c += 256) {
      int row = c >> 3, gs = (c & 7) ^ (row & 7);
      size_t off = (size_t)(n0 + row) * K + k0 + (gs << 3);
      gload16(Bh + c * 8, Bh_g + off);
      gload16(Bl + c * 8, Bl_g + off);
    }
    __syncthreads(); // drains vmcnt -> staged data visible

    #pragma unroll
    for (int ks = 0; ks < 2; ks++) {
      bf16x8 ah[MR], al[MR];
      #pragma unroll
      for (int m = 0; m < MR; m++) {
        int r = wr * (BM / 2) + m * 16 + l16;
        int sl = ((ks << 2) + rg) ^ (r & 7);
        ah[m] = *(const bf16x8*)&Ah[r * BK + (sl << 3)];
        al[m] = *(const bf16x8*)&Al[r * BK + (sl << 3)];
      }
      #pragma unroll
      for (int n = 0; n < NR; n++) {
        int r = wc * (BN / 2) + n * 16 + l16;
        int sl = ((ks << 2) + rg) ^ (r & 7);
        bf16x8 bh = *(const bf16x8*)&Bh[r * BK + (sl << 3)];
        bf16x8 bl = *(const bf16x8*)&Bl[r * BK + (sl << 3)];
        #pragma unroll
        for (int m = 0; m < MR; m++) {
          acc[m][n] = __builtin_amdgcn_mfma_f32_16x16x32_bf16(ah[m], bh, acc[m][n], 0, 0, 0);
          acc[m][n] = __builtin_amdgcn_mfma_f32_16x16x32_bf16(ah[m], bl, acc[m][n], 0, 0, 0);
          acc[m][n] = __builtin_amdgcn_mfma_f32_16x16x32_bf16(al[m], bh, acc[m][n], 0, 0, 0);
          if (TERMS == 4)
            acc[m][n] = __builtin_amdgcn_mfma_f32_16x16x32_bf16(al[m], bl, acc[m][n], 0, 0, 0);
        }
      }
    }
    __syncthreads();
  }

  int rbase = m0 + wr * (BM / 2) + (rg << 2);
  #pragma unroll
  for (int m = 0; m < MR; m++) {
    #pragma unroll
    for (int j = 0; j < 4; j++) {
      int row = rbase + m * 16 + j;
      #pragma unroll
      for (int n = 0; n < NR; n++) {
        int col = n0 + wc * (BN / 2) + n * 16 + l16;
        float v = acc[m][n][j];
        if (EPI == 1) v = v > 0.f ? v * v : 0.f;
        if (R) v += R[(size_t)row * N + col];
        if (OUTBF != 1) Cf[(size_t)row * N + col] = v;
        if (OUTBF >= 1) {
          u16 hb, lb; split_bf(v, hb, lb);
          Ch[(size_t)row * N + col] = hb;
          Cl[(size_t)row * N + col] = lb;
        }
      }
    }
  }
}

// ---------------- fused q|k|v|g GEMM: N = 3*1024 + 64(padded g), 4-term split-bf16 ---------
__global__ __launch_bounds__(256) void k_mfma_qkvg(
    const u16* __restrict__ Ahg, const u16* __restrict__ Alg,
    const u16* __restrict__ BqH, const u16* __restrict__ BqL,
    const u16* __restrict__ BkH, const u16* __restrict__ BkL,
    const u16* __restrict__ BvH, const u16* __restrict__ BvL,
    const u16* __restrict__ BgH, const u16* __restrict__ BgL,
    float* __restrict__ qo, float* __restrict__ ko, float* __restrict__ vo,
    float* __restrict__ gpre, u16* __restrict__ qbh, u16* __restrict__ qbl)
{
  constexpr int BM = 64, BN = 64, BK = 64, K = cD;
  __shared__ u16 lds[(BM + BN) * BK * 2];
  u16* Ah = lds;
  u16* Al = Ah + BM * BK;
  u16* Bh = Al + BM * BK;
  u16* Bl = Bh + BN * BK;

  int tid = threadIdx.x;
  int lane = tid & 63, wave = tid >> 6;
  int wr = wave >> 1, wc = wave & 1;
  int l16 = lane & 15, rg = lane >> 4;

  int nwg = gridDim.x * gridDim.y; // 1568 = 8*196
  int lin = blockIdx.y * gridDim.x + blockIdx.x;
  lin = (lin & 7) * (nwg >> 3) + (lin >> 3);
  int bx = lin % gridDim.x, by = lin / gridDim.x;
  int mat = bx >> 4; // 0=q 1=k 2=v 3=g (bx==48)
  int n0 = (bx - (mat << 4)) * BN;
  int m0 = by * BM;

  const u16* Bh_g; const u16* Bl_g;
  if (mat == 0)      { Bh_g = BqH; Bl_g = BqL; }
  else if (mat == 1) { Bh_g = BkH; Bl_g = BkL; }
  else if (mat == 2) { Bh_g = BvH; Bl_g = BvL; }
  else               { Bh_g = BgH; Bl_g = BgL; }

  f32x4 acc[2][2];
  #pragma unroll
  for (int m = 0; m < 2; m++)
    #pragma unroll
    for (int n = 0; n < 2; n++) acc[m][n] = (f32x4){0.f, 0.f, 0.f, 0.f};

  for (int k0 = 0; k0 < K; k0 += BK) {
    #pragma unroll
    for (int c = tid; c < BM * 8; c += 256) {
      int row = c >> 3, gs = (c & 7) ^ (row & 7);
      size_t off = (size_t)(m0 + row) * K + k0 + (gs << 3);
      gload16(Ah + c * 8, Ahg + off);
      gload16(Al + c * 8, Alg + off);
    }
    #pragma unroll
    for (int c = tid; c < BN * 8; c += 256) {
      int row = c >> 3, gs = (c & 7) ^ (row & 7);
      size_t off = (size_t)(n0 + row) * K + k0 + (gs << 3);
      gload16(Bh + c * 8, Bh_g + off);
      gload16(Bl + c * 8, Bl_g + off);
    }
    __syncthreads();

    #pragma unroll
    for (int ks = 0; ks < 2; ks++) {
      bf16x8 ah[2], al[2];
      #pragma unroll
      for (int m = 0; m < 2; m++) {
        int r = wr * 32 + m * 16 + l16;
        int sl = ((ks << 2) + rg) ^ (r & 7);
        ah[m] = *(const bf16x8*)&Ah[r * BK + (sl << 3)];
        al[m] = *(const bf16x8*)&Al[r * BK + (sl << 3)];
      }
      #pragma unroll
      for (int n = 0; n < 2; n++) {
        int r = wc * 32 + n * 16 + l16;
        int sl = ((ks << 2) + rg) ^ (r & 7);
        bf16x8 bh = *(const bf16x8*)&Bh[r * BK + (sl << 3)];
        bf16x8 bl = *(const bf16x8*)&Bl[r * BK + (sl << 3)];
        #pragma unroll
        for (int m = 0; m < 2; m++) {
          acc[m][n] = __builtin_amdgcn_mfma_f32_16x16x32_bf16(ah[m], bh, acc[m][n], 0, 0, 0);
          acc[m][n] = __builtin_amdgcn_mfma_f32_16x16x32_bf16(ah[m], bl, acc[m][n], 0, 0, 0);
          acc[m][n] = __builtin_amdgcn_mfma_f32_16x16x32_bf16(al[m], bh, acc[m][n], 0, 0, 0);
          acc[m][n] = __builtin_amdgcn_mfma_f32_16x16x32_bf16(al[m], bl, acc[m][n], 0, 0, 0);
        }
      }
    }
    __syncthreads();
  }

  int rbase = m0 + wr * 32 + (rg << 2);
  #pragma unroll
  for (int m = 0; m < 2; m++) {
    #pragma unroll
    for (int j = 0; j < 4; j++) {
      int row = rbase + m * 16 + j;
      #pragma unroll
      for (int n = 0; n < 2; n++) {
        int col = n0 + wc * 32 + n * 16 + l16;
        float v = acc[m][n][j];
        if (mat == 0) {
          qo[(size_t)row * cD + col] = v;
          u16 hb, lb; split_bf(v, hb, lb);
          qbh[(size_t)row * cD + col] = hb;
          qbl[(size_t)row * cD + col] = lb;
        } else if (mat == 1) {
          ko[(size_t)row * cD + col] = v;
        } else if (mat == 2) {
          vo[(size_t)row * cD + col] = v;
        } else if (col < 48) {
          gpre[(size_t)row * 48 + col] = v;
        }
      }
    }
  }
}

// ---------------- block compression, f32 out (fallback path only) ----------------
__global__ __launch_bounds__(64) void k_compress4(
    const float* __restrict__ kbuf, const float* __restrict__ vbuf,
    const float* __restrict__ pos_k, const float* __restrict__ pos_v,
    const float* __restrict__ Wck, const float* __restrict__ Wcv,
    const float* __restrict__ mem_k, const float* __restrict__ mem_v,
    float* __restrict__ kc, float* __restrict__ vc)
{
  int idx = blockIdx.x;          // b*NBLK*H + n*H + h
  int h = idx % cH; int n = (idx / cH) % cNBLK; int b = idx / (cH * cNBLK);
  int d = threadIdx.x;
  size_t co = (((size_t)b * cNBLK + n) * cH + h) * cDH + d;
  if (n == 0) {
    kc[co] = mem_k[h * cDH + d];
    vc[co] = mem_v[h * cDH + d];
    return;
  }
  __shared__ float kb[cBS * cDH], vb[cBS * cDH];
  int nb = n - 1;
  for (int t = d; t < cBS * cDH; t += 64) {
    int i = t >> 6, e = t & 63;
    size_t src = (((size_t)b * cS + nb * cBS + i) * cH + h) * cDH + e;
    kb[t] = kbuf[src] + pos_k[(h * cBS + i) * cDH + e];
    vb[t] = vbuf[src] + pos_v[(h * cBS + i) * cDH + e];
  }
  __syncthreads();
  float ak = 0.f, av = 0.f;
  #pragma unroll 4
  for (int j = 0; j < cBS * cDH; ++j) {
    ak += kb[j] * Wck[(size_t)j * cDH + d];
    av += vb[j] * Wcv[(size_t)j * cDH + d];
  }
  kc[co] = ak; vc[co] = av;
}

// ---------------- block compression, bf16 hi/lo (4 waves/block; n is block-uniform) --------
__global__ __launch_bounds__(256) void k_compress4_bf(
    const float* __restrict__ kbuf, const float* __restrict__ vbuf,
    const float* __restrict__ pos_k, const float* __restrict__ pos_v,
    const float* __restrict__ Wck, const float* __restrict__ Wcv,
    const float* __restrict__ mem_k, const float* __restrict__ mem_v,
    u16* __restrict__ kch, u16* __restrict__ kcl,
    u16* __restrict__ vth, u16* __restrict__ vtl)
{
  int wave = threadIdx.x >> 6, d = threadIdx.x & 63;
  int idx = blockIdx.x * 4 + wave;  // 4-aligned chunks never straddle the h=16 boundary,
  int h = idx % cH;                 // so n (and b) are block-uniform.
  int n = (idx / cH) % cNBLK;
  int b = idx / (cH * cNBLK);
  float ak, av;
  if (n == 0) {
    ak = mem_k[h * cDH + d];
    av = mem_v[h * cDH + d];
    size_t vr = ((size_t)(b * cH + h) * cDH + d) * cNP;
    for (int p = cNBLK; p < cNP; p++) { vth[vr + p] = 0; vtl[vr + p] = 0; }
  } else {
    __shared__ float kb[4][cBS * cDH], vb[4][cBS * cDH];
    int nb = n - 1;
    for (int t = d; t < cBS * cDH; t += 64) {
      int i = t >> 6, e = t & 63;
      size_t src = (((size_t)b * cS + nb * cBS + i) * cH + h) * cDH + e;
      kb[wave][t] = kbuf[src] + pos_k[(h * cBS + i) * cDH + e];
      vb[wave][t] = vbuf[src] + pos_v[(h * cBS + i) * cDH + e];
    }
    __syncthreads(); // block-uniform branch
    ak = 0.f; av = 0.f;
    #pragma unroll 4
    for (int j = 0; j < cBS * cDH; ++j) {
      ak += kb[wave][j] * Wck[(size_t)j * cDH + d];
      av += vb[wave][j] * Wcv[(size_t)j * cDH + d];
    }
  }
  u16 kh, kl, vh, vl;
  split_bf(ak, kh, kl); split_bf(av, vh, vl);
  size_t kco = ((size_t)(b * cH + h) * cNP + n) * cDH + d;
  kch[kco] = kh; kcl[kco] = kl;
  size_t vco = ((size_t)(b * cH + h) * cDH + d) * cNP + n;
  vth[vco] = vh; vtl[vco] = vl;
}

// ---- cattn helpers ----
__device__ __forceinline__ void top4_insert(float sv, int bi,
    float& v0, float& v1, float& v2, float& v3, int& i0, int& i1, int& i2, int& i3)
{
  if (sv > v3) {
    if (sv > v0)      { v3=v2;i3=i2; v2=v1;i2=i1; v1=v0;i1=i0; v0=sv;i0=bi; }
    else if (sv > v1) { v3=v2;i3=i2; v2=v1;i2=i1; v1=sv;i1=bi; }
    else if (sv > v2) { v3=v2;i3=i2; v2=sv;i2=bi; }
    else              { v3=sv;i3=bi; }
  }
}

// insert with tie-break (equal value -> lower block index wins)
__device__ __forceinline__ void top4_ins_tie(float sv, int bi,
    float& v0, float& v1, float& v2, float& v3, int& i0, int& i1, int& i2, int& i3)
{
  bool b3 = (sv > v3) || (sv == v3 && bi < i3);
  if (!b3) return;
  bool b0 = (sv > v0) || (sv == v0 && bi < i0);
  bool b1 = (sv > v1) || (sv == v1 && bi < i1);
  bool b2 = (sv > v2) || (sv == v2 && bi < i2);
  if (b0)      { v3=v2;i3=i2; v2=v1;i2=i1; v1=v0;i1=i0; v0=sv;i0=bi; }
  else if (b1) { v3=v2;i3=i2; v2=v1;i2=i1; v1=sv;i1=bi; }
  else if (b2) { v3=v2;i3=i2; v2=sv;i2=bi; }
  else         { v3=sv;i3=bi; }
}

// One pass over CNT columns (fallback scalar cattn helper)
template<int CNT>
__device__ __forceinline__ void cattn_cols(
    int base, int lane, int s_row, const float* __restrict__ kcb,
    const float* __restrict__ qrow, u16* __restrict__ ssb, float& lm,
    float& v0, float& v1, float& v2, float& v3,
    int& i0, int& i1, int& i2, int& i3)
{
  float sreg[CNT];
  #pragma unroll
  for (int u = 0; u < CNT; u++) sreg[u] = 0.f;
  #pragma unroll
  for (int d0 = 0; d0 < 4; d0++) {
    float4 qc0 = ((const float4*)qrow)[d0 * 4 + 0];
    float4 qc1 = ((const float4*)qrow)[d0 * 4 + 1];
    float4 qc2 = ((const float4*)qrow)[d0 * 4 + 2];
    float4 qc3 = ((const float4*)qrow)[d0 * 4 + 3];
    #pragma unroll
    for (int u = 0; u < CNT; u++) {
      int n = base + u;
      if (n < cNBLK) {
        const float4* kp = (const float4*)(kcb + (size_t)n * (cH * cDH) + d0 * 16);
        float4 k0 = kp[0], k1 = kp[1], k2 = kp[2], k3 = kp[3];
        sreg[u] += qc0.x*k0.x + qc0.y*k0.y + qc0.z*k0.z + qc0.w*k0.w
                 + qc1.x*k1.x + qc1.y*k1.y + qc1.z*k1.z + qc1.w*k1.w
                 + qc2.x*k2.x + qc2.y*k2.y + qc2.z*k2.z + qc2.w*k2.w
                 + qc3.x*k3.x + qc3.y*k3.y + qc3.z*k3.z + qc3.w*k3.w;
      }
    }
  }
  #pragma unroll
  for (int u = 0; u < CNT; u++) {
    int n = base + u;
    if (n >= cNBLK) continue;
    float a = sreg[u] * cSCALE;
    bool vis = (n == 0) || ((n - 1) * cBS + (cBS - 1) <= s_row);
    float sv = vis ? a : -INFINITY;
    ssb[lane * cSSTR + n] = f2b(sv);
    lm = fmaxf(lm, sv);
    if (n >= 1) top4_insert(sv, n - 1, v0, v1, v2, v3, i0, i1, i2, i3);
  }
}

// ---------------- scalar compressed attention (fallback path only) ----------------
__global__ __launch_bounds__(512, 4) void k_cattn_tile(
    const float* __restrict__ q, const float* __restrict__ kc, const float* __restrict__ vc,
    float* __restrict__ cout, float* __restrict__ sel_val, int* __restrict__ sel_idx)
{
  constexpr int NW = 8;
  constexpr int NCH = 33;
  __shared__ u16  ssb[64 * cSSTR];
  __shared__ float lmax[NW][64];
  __shared__ float lsum[NW][64];
  __shared__ float t4v[NW][64][4];
  __shared__ int   t4i[NW][64][4];
  __shared__ float mxs[64];
  __shared__ float invs[64];

  int tile = blockIdx.x & 15;
  int h = (blockIdx.x >> 4) & 15;
  int b = blockIdx.x >> 8;
  int s0 = tile * 64;
  int t = threadIdx.x;
  int lane = t & 63, wave = t >> 6;

  const float* kcb = kc + ((size_t)b * cNBLK * cH + h) * cDH;
  const float* vcb = vc + ((size_t)b * cNBLK * cH + h) * cDH;
  const int nstride = cH * cDH;

  {
    int r = lane;
    int s_row = s0 + r;
    const float* qrow = q + (((size_t)b * cS + s_row) * cH + h) * cDH;
    float v0=-INFINITY,v1=-INFINITY,v2=-INFINITY,v3=-INFINITY;
    int i0=0,i1=0,i2=0,i3=0;
    float lm = -INFINITY;
    int nb0 = wave * NCH;
    cattn_cols<11>(nb0,      r, s_row, kcb, qrow, ssb, lm, v0,v1,v2,v3, i0,i1,i2,i3);
    cattn_cols<11>(nb0 + 11, r, s_row, kcb, qrow, ssb, lm, v0,v1,v2,v3, i0,i1,i2,i3);
    cattn_cols<11>(nb0 + 22, r, s_row, kcb, qrow, ssb, lm, v0,v1,v2,v3, i0,i1,i2,i3);
    lmax[wave][lane] = lm;
    t4v[wave][lane][0]=v0; t4v[wave][lane][1]=v1; t4v[wave][lane][2]=v2; t4v[wave][lane][3]=v3;
    t4i[wave][lane][0]=i0; t4i[wave][lane][1]=i1; t4i[wave][lane][2]=i2; t4i[wave][lane][3]=i3;
  }
  __syncthreads();

  if (wave == 0) {
    int r = lane;
    float mx = -INFINITY;
    #pragma unroll
    for (int c = 0; c < NW; c++) mx = fmaxf(mx, lmax[c][r]);
    mxs[r] = mx;
    float v0=-INFINITY,v1=-INFINITY,v2=-INFINITY,v3=-INFINITY;
    int i0=0,i1=0,i2=0,i3=0;
    #pragma unroll
    for (int c = 0; c < NW; c++)
      #pragma unroll
      for (int u = 0; u < 4; u++)
        top4_insert(t4v[c][r][u], t4i[c][r][u], v0, v1, v2, v3, i0, i1, i2, i3);
    t4v[0][r][0]=v0; t4v[0][r][1]=v1; t4v[0][r][2]=v2; t4v[0][r][3]=v3;
    t4i[0][r][0]=i0; t4i[0][r][1]=i1; t4i[0][r][2]=i2; t4i[0][r][3]=i3;
  }
  __syncthreads();

  {
    int r = lane;
    float mx = mxs[r];
    float s = 0.f;
    int nb0 = wave * NCH;
    int nb1 = min(cNBLK, nb0 + NCH);
    for (int n = nb0; n < nb1; n++) {
      float sv = b2f(ssb[r * cSSTR + n]);
      float e = expf(sv - mx);
      ssb[r * cSSTR + n] = f2b(e);
      s += e;
    }
    lsum[wave][r] = s;
  }
  __syncthreads();

  if (wave == 0) {
    int r = lane;
    float sum = 0.f;
    #pragma unroll
    for (int c = 0; c < NW; c++) sum += lsum[c][r];
    float inv = 1.f / sum;
    invs[r] = inv;
    float mx = mxs[r];
    size_t so = (((size_t)b * cH + h) * cS + (s0 + r)) * cNSEL;
    #pragma unroll
    for (int u = 0; u < 4; u++) {
      sel_val[so + u] = expf(t4v[0][r][u] - mx) * inv;
      sel_idx[so + u] = t4i[0][r][u];
    }
  }
  __syncthreads();

  {
    int r = t >> 3, dq = t & 7;
    float4 a0 = {0,0,0,0}, a1 = {0,0,0,0};
    const u16* erow = ssb + r * cSSTR;
    const float* vbase = vcb + dq * 8;
#define ACC8(ee, w0, w1) \
    a0.x += (ee)*(w0).x; a0.y += (ee)*(w0).y; a0.z += (ee)*(w0).z; a0.w += (ee)*(w0).w; \
    a1.x += (ee)*(w1).x; a1.y += (ee)*(w1).y; a1.z += (ee)*(w1).z; a1.w += (ee)*(w1).w;
    for (int n = 0; n < 256; n += 4) {
      float e0 = b2f(erow[n+0]), e1 = b2f(erow[n+1]);
      float e2 = b2f(erow[n+2]), e3 = b2f(erow[n+3]);
      const float4* p0 = (const float4*)(vbase + (size_t)(n+0) * nstride);
      const float4* p1 = (const float4*)(vbase + (size_t)(n+1) * nstride);
      const float4* p2 = (const float4*)(vbase + (size_t)(n+2) * nstride);
      const float4* p3 = (const float4*)(vbase + (size_t)(n+3) * nstride);
      float4 w00 = p0[0], w01 = p0[1];
      float4 w10 = p1[0], w11 = p1[1];
      float4 w20 = p2[0], w21 = p2[1];
      float4 w30 = p3[0], w31 = p3[1];
      ACC8(e0, w00, w01)
      ACC8(e1, w10, w11)
      ACC8(e2, w20, w21)
      ACC8(e3, w30, w31)
    }
    {
      float e0 = b2f(erow[256]);
      const float4* p0 = (const float4*)(vbase + (size_t)256 * nstride);
      float4 w00 = p0[0], w01 = p0[1];
      ACC8(e0, w00, w01)
    }
#undef ACC8
    float inv = invs[r];
    float* crow = cout + (((size_t)b * cS + s0 + r) * cH + h) * cDH + dq * 8;
    ((float4*)crow)[0] = make_float4(a0.x*inv, a0.y*inv, a0.z*inv, a0.w*inv);
    ((float4*)crow)[1] = make_float4(a1.x*inv, a1.y*inv, a1.z*inv, a1.w*inv);
  }
}

// ---------------- MFMA compressed attention v5: 2-wave blocks for 2x occupancy -------------
// v3's exact per-wave math (bitwise-same output), re-partitioned: 1024 blocks x 128 thr,
// each wave owns a 16-row s-tile. LDS 18.9KB -> 8 blocks/CU = 16 waves/CU (2x v3/v4).
// Direct global kc/vt reads (L2-resident; XCD swizzle clusters same-(b,h) blocks).
__global__ __launch_bounds__(128) void k_cattn_mfma(
    const u16* __restrict__ qbh, const u16* __restrict__ qbl,
    const u16* __restrict__ kch, const u16* __restrict__ kcl,
    const u16* __restrict__ vth, const u16* __restrict__ vtl,
    float* __restrict__ cout, float* __restrict__ sel_val, int* __restrict__ sel_idx)
{
  constexpr int SSTW = 296; // u16 stride per s-row: 592B = 37*16B (b128-aligned rows)
  __shared__ u16 sws[2 * 16 * SSTW]; // 18944B

  int bid = (blockIdx.x & 7) * 128 + (blockIdx.x >> 3); // XCD-bijective (1024 = 8*128)
  int lane = threadIdx.x & 63, w = threadIdx.x >> 6;    // w in {0,1}
  int l16 = lane & 15, rg = lane >> 4, g8 = rg << 3;
  int t32 = bid & 31;                  // 32 s-blocks of 32 rows... t32 indexes 32-row pairs
  int h = (bid >> 5) & 15, b = bid >> 9;
  int s0 = t32 * 32 + w * 16;          // wave's 16-row tile
  u16* sraw = sws + w * 16 * SSTW;     // per-wave [16 s][SSTW n]

  // B-frag: q row s = s0 + l16 (pre-rope split-bf16)
  size_t qrow = (((size_t)b * cS + (s0 + l16)) * cH + h) * cDH;
  bf16x8 qh0 = *(const bf16x8*)(qbh + qrow + g8);
  bf16x8 qh1 = *(const bf16x8*)(qbh + qrow + 32 + g8);
  bf16x8 ql0 = *(const bf16x8*)(qbl + qrow + g8);
  bf16x8 ql1 = *(const bf16x8*)(qbl + qrow + 32 + g8);

  const u16* kchb = kch + (size_t)(b * cH + h) * cNP * cDH;
  const u16* kclb = kcl + (size_t)(b * cH + h) * cNP * cDH;

  float v0=-INFINITY, v1=-INFINITY, v2=-INFINITY, v3=-INFINITY;
  int i0=0, i1=0, i2=0, i3=0;
  float lm = -INFINITY;

  // ---- scores: lane-local selection, raw bf16 -> LDS ----
  for (int nt = 0; nt < 18; nt++) {
    size_t krow = (size_t)(nt * 16 + l16) * cDH; // A row = n
    bf16x8 kh0 = *(const bf16x8*)(kchb + krow + g8);
    bf16x8 kh1 = *(const bf16x8*)(kchb + krow + 32 + g8);
    bf16x8 kl0 = *(const bf16x8*)(kclb + krow + g8);
    bf16x8 kl1 = *(const bf16x8*)(kclb + krow + 32 + g8);
    f32x4 acc = (f32x4){0.f, 0.f, 0.f, 0.f};
    acc = __builtin_amdgcn_mfma_f32_16x16x32_bf16(kh0, qh0, acc, 0, 0, 0);
    acc = __builtin_amdgcn_mfma_f32_16x16x32_bf16(kh1, qh1, acc, 0, 0, 0);
    acc = __builtin_amdgcn_mfma_f32_16x16x32_bf16(kh0, ql0, acc, 0, 0, 0);
    acc = __builtin_amdgcn_mfma_f32_16x16x32_bf16(kh1, ql1, acc, 0, 0, 0);
    acc = __builtin_amdgcn_mfma_f32_16x16x32_bf16(kl0, qh0, acc, 0, 0, 0);
    acc = __builtin_amdgcn_mfma_f32_16x16x32_bf16(kl1, qh1, acc, 0, 0, 0);
    acc = __builtin_amdgcn_mfma_f32_16x16x32_bf16(kl0, ql0, acc, 0, 0, 0);
    acc = __builtin_amdgcn_mfma_f32_16x16x32_bf16(kl1, ql1, acc, 0, 0, 0);
    // D: col = l16 -> s-row; row = rg*4+j -> n
    u16 sb[4];
    #pragma unroll
    for (int j = 0; j < 4; j++) {
      int n = nt * 16 + rg * 4 + j;
      float a = acc[j] * cSCALE;
      bool vis = (n < cNBLK) && ((n == 0) || ((n - 1) * cBS + (cBS - 1) <= s0 + l16));
      float sv = vis ? a : -INFINITY;
      sb[j] = f2b(sv);
      lm = fmaxf(lm, sv);
      if (n >= 1) top4_ins_tie(sv, n - 1, v0, v1, v2, v3, i0, i1, i2, i3);
    }
    int cw = nt * 16 + rg * 4;
    *(u32*)&sraw[l16 * SSTW + cw]     = (u32)sb[0] | ((u32)sb[1] << 16);
    *(u32*)&sraw[l16 * SSTW + cw + 2] = (u32)sb[2] | ((u32)sb[3] << 16);
  }

  // ---- merge across the 4 rg-replicas of each s-row (lanes xor 16, 32) ----
  #pragma unroll
  for (int o = 16; o < 64; o <<= 1) {
    lm = fmaxf(lm, __shfl_xor(lm, o));
    float p0 = __shfl_xor(v0, o), p1 = __shfl_xor(v1, o);
    float p2 = __shfl_xor(v2, o), p3 = __shfl_xor(v3, o);
    int   q0 = __shfl_xor(i0, o), q1 = __shfl_xor(i1, o);
    int   q2 = __shfl_xor(i2, o), q3 = __shfl_xor(i3, o);
    top4_ins_tie(p0, q0, v0, v1, v2, v3, i0, i1, i2, i3);
    top4_ins_tie(p1, q1, v0, v1, v2, v3, i0, i1, i2, i3);
    top4_ins_tie(p2, q2, v0, v1, v2, v3, i0, i1, i2, i3);
    top4_ins_tie(p3, q3, v0, v1, v2, v3, i0, i1, i2, i3);
  }

  // ---- exp + sum over this lane's 72 owned values; e overwrites LDS ----
  float sum = 0.f;
  for (int nt = 0; nt < 18; nt++) {
    int cw = nt * 16 + rg * 4;
    u32 w01 = *(u32*)&sraw[l16 * SSTW + cw];
    u32 w23 = *(u32*)&sraw[l16 * SSTW + cw + 2];
    float e0 = expf(b2f((u16)(w01 & 0xffff)) - lm);
    float e1 = expf(b2f((u16)(w01 >> 16)) - lm);
    float e2 = expf(b2f((u16)(w23 & 0xffff)) - lm);
    float e3 = expf(b2f((u16)(w23 >> 16)) - lm);
    sum += (e0 + e1) + (e2 + e3);
    *(u32*)&sraw[l16 * SSTW + cw]     = (u32)f2b(e0) | ((u32)f2b(e1) << 16);
    *(u32*)&sraw[l16 * SSTW + cw + 2] = (u32)f2b(e2) | ((u32)f2b(e3) << 16);
  }
  #pragma unroll
  for (int o = 16; o < 64; o <<= 1) sum += __shfl_xor(sum, o);
  float inv = 1.f / sum;

  if (rg == 0) {
    size_t so = (((size_t)b * cH + h) * cS + (s0 + l16)) * cNSEL;
    sel_val[so + 0] = expf(v0 - lm) * inv; sel_idx[so + 0] = i0;
    sel_val[so + 1] = expf(v1 - lm) * inv; sel_idx[so + 1] = i1;
    sel_val[so + 2] = expf(v2 - lm) * inv; sel_idx[so + 2] = i2;
    sel_val[so + 3] = expf(v3 - lm) * inv; sel_idx[so + 3] = i3;
  }
  __syncthreads(); // e visible across lanes (cheap: 2 waves)

  // ---- PV: out^T = mfma(vc^T, e), K = 288 (e pad = 0, vt pad zeroed) ----
  const u16* vthb = vth + (size_t)(b * cH + h) * cDH * cNP;
  const u16* vtlb = vtl + (size_t)(b * cH + h) * cDH * cNP;
  f32x4 pacc[4];
  #pragma unroll
  for (int dt = 0; dt < 4; dt++) pacc[dt] = (f32x4){0.f, 0.f, 0.f, 0.f};
  for (int kc9 = 0; kc9 < 9; kc9++) {
    // B-frag: e row s = l16, k-granule n = kc9*32 + g8 (16B-aligned)
    bf16x8 ef = *(const bf16x8*)&sraw[l16 * SSTW + kc9 * 32 + g8];
    #pragma unroll
    for (int dt = 0; dt < 4; dt++) {
      size_t vrow = (size_t)(dt * 16 + l16) * cNP + kc9 * 32 + g8; // A row = d
      bf16x8 vh = *(const bf16x8*)(vthb + vrow);
      bf16x8 vl = *(const bf16x8*)(vtlb + vrow);
      pacc[dt] = __builtin_amdgcn_mfma_f32_16x16x32_bf16(vh, ef, pacc[dt], 0, 0, 0);
      pacc[dt] = __builtin_amdgcn_mfma_f32_16x16x32_bf16(vl, ef, pacc[dt], 0, 0, 0);
    }
  }
  // D: col = l16 -> s; row = rg*4+j -> d = dt*16 + rg*4 + j (j consecutive -> float4)
  float* crow = cout + (((size_t)b * cS + (s0 + l16)) * cH + h) * cDH;
  #pragma unroll
  for (int dt = 0; dt < 4; dt++) {
    *(float4*)(crow + dt * 16 + rg * 4) =
        make_float4(pacc[dt][0] * inv, pacc[dt][1] * inv,
                    pacc[dt][2] * inv, pacc[dt][3] * inv);
  }
}

// ---------------- in-place RoPE on q and k ----------------
__global__ __launch_bounds__(256) void k_rope(float* __restrict__ q, float* __restrict__ k)
{
  int t = blockIdx.x * 256 + threadIdx.x;
  int j = t & 31; int h = (t >> 5) & (cH - 1); int bs = t >> 9;
  int s = bs & (cS - 1);
  float inv = expf(-(float)j * 0.28782313662425575f);
  float ang = (float)s * inv;
  float sn, c; sincosf(ang, &sn, &c);
  size_t base = ((size_t)bs * cH + h) * cDH;
  float q1 = q[base + j], q2 = q[base + j + 32];
  q[base + j]      = q1 * c - q2 * sn;
  q[base + j + 32] = q1 * sn + q2 * c;
  float k1 = k[base + j], k2 = k[base + j + 32];
  k[base + j]      = k1 * c - k2 * sn;
  k[base + j + 32] = k1 * sn + k2 * c;
}

// ---------------- fused fine + sliding-window attention ----------------
__global__ __launch_bounds__(256) void k_fsattn(
    const float* __restrict__ qr, const float* __restrict__ kr, const float* __restrict__ v,
    const float* __restrict__ sel_val, const int* __restrict__ sel_idx,
    float* __restrict__ fout, float* __restrict__ sout)
{
  int wave = threadIdx.x >> 6, lane = threadIdx.x & 63;
  int sidx = blockIdx.x * 4 + wave;
  int s = sidx % cS; int h = (sidx / cS) % cH; int b = sidx / (cS * cH);
  __shared__ float qs[4][cDH];
  __shared__ float pf[4][20];
  __shared__ float ps[4][cWIN];
  __shared__ int blk[4][5];
  __shared__ int bok[4][5];
  size_t qoff = (((size_t)b * cS + s) * cH + h) * cDH;
  qs[wave][lane] = qr[qoff + lane];
  if (lane < 5) {
    size_t so = (((size_t)b * cH + h) * cS + s) * cNSEL;
    if (lane < 4) { blk[wave][lane] = sel_idx[so + lane]; bok[wave][lane] = sel_val[so + lane] > 0.f; }
    else          { blk[wave][4] = s / cBS; bok[wave][4] = 1; }
  }
  __syncthreads();

  const float* kp = nullptr;
  if (lane < 20) {
    int tt = lane >> 2, i = lane & 3;
    int kpos = blk[wave][tt] * cBS + i;
    if (bok[wave][tt] && kpos <= s)
      kp = kr + (((size_t)b * cS + kpos) * cH + h) * cDH;
  } else if (lane >= 32) {
    int sp = s - (lane - 32);
    if (sp >= 0)
      kp = kr + (((size_t)b * cS + sp) * cH + h) * cDH;
  }
  float sc = -INFINITY;
  if (kp) {
    float a = 0.f;
    #pragma unroll 16
    for (int e = 0; e < cDH; e++) a += qs[wave][e] * kp[e];
    sc = a * cSCALE;
  }
  float mx = sc;
  #pragma unroll
  for (int o = 16; o; o >>= 1) mx = fmaxf(mx, __shfl_xor(mx, o, 32));
  float ex = (sc == -INFINITY) ? 0.f : expf(sc - mx);
  float sum = ex;
  #pragma unroll
  for (int o = 16; o; o >>= 1) sum += __shfl_xor(sum, o, 32);
  float pp = ex / sum;
  if (lane < 20) pf[wave][lane] = pp;
  if (lane >= 32) ps[wave][lane - 32] = pp;
  __syncthreads();

  float accf = 0.f;
  for (int tt = 0; tt < 5; tt++) {
    if (!bok[wave][tt]) continue;
    int kbase = blk[wave][tt] * cBS;
    #pragma unroll
    for (int i = 0; i < cBS; i++) {
      float pm = pf[wave][tt * cBS + i];
      if (pm != 0.f)
        accf += pm * v[(((size_t)b * cS + kbase + i) * cH + h) * cDH + lane];
    }
  }
  float accs = 0.f;
  int wm = min(cWIN, s + 1);
  for (int w = 0; w < wm; w++)
    accs += ps[wave][w] * v[(((size_t)b * cS + s - w) * cH + h) * cDH + lane];
  fout[qoff + lane] = accf;
  sout[qoff + lane] = accs;
}

// ---------------- gated combine (f32 out, fallback) ----------------
__global__ __launch_bounds__(256) void k_combine(
    const float* __restrict__ gpre, const float* __restrict__ cout,
    const float* __restrict__ fout, const float* __restrict__ sout, float* __restrict__ o)
{
  int t = blockIdx.x * 256 + threadIdx.x;
  int hh = (t >> 6) & 15; int bs = t >> 10;
  float g0 = sigf(gpre[(size_t)bs * 48 + hh * 3 + 0]);
  float g1 = sigf(gpre[(size_t)bs * 48 + hh * 3 + 1]);
  float g2 = sigf(gpre[(size_t)bs * 48 + hh * 3 + 2]);
  o[t] = g0 * cout[t] + g1 * fout[t] + g2 * sout[t];
}

// ---------------- gated combine -> bf16 hi/lo (feeds Wo MFMA GEMM) ----------------
__global__ __launch_bounds__(256) void k_combine_bf(
    const float* __restrict__ gpre, const float* __restrict__ cout,
    const float* __restrict__ fout, const float* __restrict__ sout,
    u16* __restrict__ oh, u16* __restrict__ ol)
{
  int t = blockIdx.x * 256 + threadIdx.x;
  int hh = (t >> 6) & 15; int bs = t >> 10;
  float g0 = sigf(gpre[(size_t)bs * 48 + hh * 3 + 0]);
  float g1 = sigf(gpre[(size_t)bs * 48 + hh * 3 + 1]);
  float g2 = sigf(gpre[(size_t)bs * 48 + hh * 3 + 2]);
  float v = g0 * cout[t] + g1 * fout[t] + g2 * sout[t];
  u16 hb, lb; split_bf(v, hb, lb);
  oh[t] = hb; ol[t] = lb;
}

extern "C" void kernel_launch(void* const* d_in, const int* in_sizes, int n_in,
                              void* d_out, int out_size, void* d_ws, size_t ws_size,
                              hipStream_t stream) {
  float* out = (float*)d_out;

  static const int exp_sizes[17] = {
    2097152, 2097152, 2097152, 2,
    1048576, 1048576, 1048576,
    4096, 4096,
    16384, 16384,
    1024, 1024,
    49152, 1048576, 4194304, 4194304
  };
  if (n_in < 17) {
    k_fill<<<dim3(8192), dim3(256), 0, stream>>>(out, 500.0f + 10.0f * n_in);
    return;
  }
  for (int i = 0; i < 17; ++i) {
    if (in_sizes[i] != exp_sizes[i] && in_sizes[i] != 4 * exp_sizes[i]) {
      k_fill<<<dim3(8192), dim3(256), 0, stream>>>(out, 1000.0f + 50.0f * i);
      return;
    }
  }

  const float* x     = (const float*)d_in[0];
  const float* x0    = (const float*)d_in[2];
  const float* lam   = (const float*)d_in[3];
  const float* Wq    = (const float*)d_in[4];
  const float* Wk    = (const float*)d_in[5];
  const float* Wv    = (const float*)d_in[6];
  const float* pos_k = (const float*)d_in[7];
  const float* pos_v = (const float*)d_in[8];
  const float* Wck   = (const float*)d_in[9];
  const float* Wcv   = (const float*)d_in[10];
  const float* mem_k = (const float*)d_in[11];
  const float* mem_v = (const float*)d_in[12];
  const float* Wg    = (const float*)d_in[13];
  const float* Wo    = (const float*)d_in[14];
  const float* Wfc   = (const float*)d_in[15];
  const float* Wpr   = (const float*)d_in[16];

  float* ws = (float*)d_ws;
  const size_t E = (size_t)cM * cD; // 2097152
  float* gpre = ws;                                   // 98304
  float* selv = ws + 98304;                           // 131072
  int*   seli = (int*)(ws + 98304 + 131072);          // 131072
  // slack region: ws+360448 .. ws+1048576 — holds padded WgT (65536 floats)
  u16* WgTh = (u16*)(ws + 360448);
  u16* WgTl = WgTh + 65536;
  const size_t A0 = 1048576;
  float* xr = ws + A0 + 0 * E;
  float* h  = ws + A0 + 1 * E; // f32 h; later reused as m_bf (hi/lo) in mfma path
  float* q  = ws + A0 + 2 * E; // roped in place; later fc_bf hi
  float* k  = ws + A0 + 3 * E;
  float* v  = ws + A0 + 4 * E;
  float* co = ws + A0 + 5 * E; // cout
  float* fo = ws + A0 + 6 * E; // kc_bf/vt_bf first, then fout
  float* so = ws + A0 + 7 * E; // q_bf first, then sout
  float* x1 = ws + A0 + 8 * E;
  float* fc = ws + A0 + 2 * E; // fallback f32 fc alias over q,k,v,co
  float* kc = fo;              // fallback f32 kc/vc aliases
  float* vc = so;

  // ---- bf16 region (beyond the legacy 76MB layout) ----
  const size_t P = A0 + 9 * E; // 19,922,944 floats
  const size_t NEED_FLOATS = P + 14680064; // unchanged vs rounds 1-9
  bool use_mfma = (ws_size >= NEED_FLOATS * sizeof(float));

  u16* WvTh = (u16*)(ws + P);              u16* WvTl = WvTh + 1048576;
  u16* WoTh = (u16*)(ws + P + 1048576);    u16* WoTl = WoTh + 1048576;
  u16* WfcTh = (u16*)(ws + P + 2097152);   u16* WfcTl = WfcTh + 4194304;
  u16* WprTh = (u16*)(ws + P + 6291456);   u16* WprTl = WprTh + 4194304;
  u16* hbh = (u16*)(ws + P + 10485760);    u16* hbl = hbh + 2097152;
  u16* obh = (u16*)(ws + P + 12582912);    u16* obl = obh + 2097152;
  u16* mbh = (u16*)h;                      u16* mbl = mbh + 2097152;   // alias h (dead)
  u16* fbh = (u16*)q;                      u16* fbl = fbh + 8388608;   // alias q..co (dead)
  // WqT/WkT alias x1 (dead until the Wo GEMM overwrites it)
  u16* WqTh = (u16*)x1;                    u16* WqTl = WqTh + 1048576;
  u16* WkTh = WqTh + 2097152;              u16* WkTl = WqTh + 3145728;
  // cattn bf16 buffers alias fo/so (dead until fsattn writes fout/sout AFTER cattn)
  const size_t KCN = (size_t)cB * cH * cNP * cDH; // 589824 u16
  u16* kch = (u16*)fo;       u16* kcl = kch + KCN;
  u16* vth = kcl + KCN;      u16* vtl = vth + KCN;   // total 2.36M u16 < E floats
  u16* qbh = (u16*)so;       u16* qbl = qbh + 2097152; // 2x2M u16 = E floats exactly

  dim3 b256(256), b64(64), b512(512), b128(128);
  dim3 gSq(cD / 64, cM / 64);

  if (use_mfma) {
    // one-time-per-launch weight transpose + hi/lo split
    k_wsplit_t<<<dim3(32, 32), b256, 0, stream>>>(Wq, WqTh, WqTl, 1024, 1024);
    k_wsplit_t<<<dim3(32, 32), b256, 0, stream>>>(Wk, WkTh, WkTl, 1024, 1024);
    k_wsplit_t<<<dim3(32, 32), b256, 0, stream>>>(Wv, WvTh, WvTl, 1024, 1024);
    k_wsplit_t<<<dim3(32, 32), b256, 0, stream>>>(Wo, WoTh, WoTl, 1024, 1024);
    k_wsplit_t<<<dim3(128, 32), b256, 0, stream>>>(Wfc, WfcTh, WfcTl, 1024, 4096);
    k_wsplit_t<<<dim3(32, 128), b256, 0, stream>>>(Wpr, WprTh, WprTl, 4096, 1024);
    k_wsplit_g<<<dim3(256), b256, 0, stream>>>(Wg, WgTh, WgTl);

    k_lerp_rmsnorm<<<dim3(cM), b256, 0, stream>>>(x, x0, lam, xr, h, hbh, hbl);

    // fused q|k|v|g GEMM (4-term split-bf16); q also emits pre-rope bf16 hi/lo
    k_mfma_qkvg<<<dim3(49, 32), b256, 0, stream>>>(
        hbh, hbl, WqTh, WqTl, WkTh, WkTl, WvTh, WvTl, WgTh, WgTl,
        q, k, v, gpre, qbh, qbl);

    k_compress4_bf<<<dim3(cB * cNBLK * cH / 4), b256, 0, stream>>>(
        k, v, pos_k, pos_v, Wck, Wcv, mem_k, mem_v, kch, kcl, vth, vtl);
    // v5: 1024 blocks x 128 threads (2 waves), 8 blocks/CU
    k_cattn_mfma<<<dim3(cB * cH * 32), b128, 0, stream>>>(
        qbh, qbl, kch, kcl, vth, vtl, co, selv, seli);
    k_rope<<<dim3(cB * cS * cH * 32 / 256), b256, 0, stream>>>(q, k);
    k_fsattn<<<dim3(cB * cH * cS / 4), b256, 0, stream>>>(q, k, v, selv, seli, fo, so);

    k_combine_bf<<<dim3((cM * cD) / 256), b256, 0, stream>>>(gpre, co, fo, so, obh, obl);

    // x1 = o @ Wo + xr  (BM=32 -> 1024 blocks = 4/CU)
    k_mfma_gemm<32, 64, 0, 0, 3><<<dim3(cD / 64, cM / 32), b256, 0, stream>>>(
        obh, obl, WoTh, WoTl, xr, x1, nullptr, nullptr, cM, cD, cD);

    // m = rmsnorm(x1) -> bf16 hi/lo only (into dead h region)
    k_rmsnorm<<<dim3(cM), b256, 0, stream>>>(x1, nullptr, mbh, mbl);

    // fc = relu(m @ Wfc)^2 -> bf16 hi/lo directly (into dead q..co region)
    k_mfma_gemm<64, 128, 1, 1, 3><<<dim3(cDFF / 128, cM / 64), b256, 0, stream>>>(
        mbh, mbl, WfcTh, WfcTl, nullptr, nullptr, fbh, fbl, cM, cDFF, cD);

    // out = fc @ Wproj + x1  (BM=32 -> 1024 blocks = 4/CU)
    k_mfma_gemm<32, 64, 0, 0, 3><<<dim3(cD / 64, cM / 32), b256, 0, stream>>>(
        fbh, fbl, WprTh, WprTl, x1, out, nullptr, nullptr, cM, cD, cDFF);
  } else {
    // fallback: all-fp32 path
    k_lerp_rmsnorm<<<dim3(cM), b256, 0, stream>>>(x, x0, lam, xr, h, nullptr, nullptr);
    k_gemm<0><<<gSq, b256, 0, stream>>>(h, Wq, nullptr, q, cM, cD, cD);
    k_gemm<0><<<gSq, b256, 0, stream>>>(h, Wk, nullptr, k, cM, cD, cD);
    k_gemm<0><<<gSq, b256, 0, stream>>>(h, Wv, nullptr, v, cM, cD, cD);
    k_gemm<0><<<dim3(1, cM / 64), b256, 0, stream>>>(h, Wg, nullptr, gpre, cM, 48, cD);
    k_compress4<<<dim3(cB * cNBLK * cH), b64, 0, stream>>>(k, v, pos_k, pos_v, Wck, Wcv,
                                                           mem_k, mem_v, kc, vc);
    k_cattn_tile<<<dim3(cB * cH * 16), b512, 0, stream>>>(q, kc, vc, co, selv, seli);
    k_rope<<<dim3(cB * cS * cH * 32 / 256), b256, 0, stream>>>(q, k);
    k_fsattn<<<dim3(cB * cH * cS / 4), b256, 0, stream>>>(q, k, v, selv, seli, fo, so);
    k_combine<<<dim3((cM * cD) / 256), b256, 0, stream>>>(gpre, co, fo, so, co);
    k_gemm<0><<<gSq, b256, 0, stream>>>(co, Wo, xr, x1, cM, cD, cD);
    k_rmsnorm<<<dim3(cM), b256, 0, stream>>>(x1, h, nullptr, nullptr);
    k_gemm<1><<<dim3(cDFF / 64, cM / 64), b256, 0, stream>>>(h, Wfc, nullptr, fc, cM, cDFF, cD);
    k_gemm<0><<<gSq, b256, 0, stream>>>(fc, Wpr, x1, out, cM, cD, cDFF);
  }
}